// Round 8
// baseline (673.633 us; speedup 1.0000x reference)
//
#include <hip/hip_runtime.h>
#include <hip/hip_bf16.h>
#include <math.h>

#define NND 50000
#define NE  1200000
#define TOT (NE + NND)
#define INCH 128
#define HID 64
#define H2  32
#define NL  3
#define BSZ 10000
#define NB  196          // ceil(NND/256) dst-buckets of 256 nodes
#define NHB 128          // bhist partial blocks
#define NSTAT 256        // bn_stats partial blocks
#define CHUNK 2048       // edges per passA block
#define EPS_RES 0.1f
#define BN_EPS 1e-5f

__device__ __forceinline__ float b2f(unsigned short u) {
    return __uint_as_float((unsigned)u << 16);
}

// ---------------- binned CSR build ----------------

// per-block partial bucket histograms (no global atomics, no memset needed)
__global__ __launch_bounds__(256) void bhist_kernel(const int* __restrict__ dst, int* __restrict__ bh_part, int ne) {
    __shared__ int arr[256];
    arr[threadIdx.x] = 0;
    __syncthreads();
    int i = blockIdx.x * 256 + threadIdx.x;
    int stride = gridDim.x * 256;
    for (int e = i; e < ne; e += stride) atomicAdd(&arr[dst[e] >> 8], 1);
    __syncthreads();
    bh_part[blockIdx.x * 256 + threadIdx.x] = arr[threadIdx.x];
}

// reduce partials + exclusive scan -> bstart/bcur; also seeds offsets[NND]
__global__ __launch_bounds__(256) void bscan_kernel(const int* __restrict__ bh_part,
                                                    int* __restrict__ bstart, int* __restrict__ bcur,
                                                    int* __restrict__ offsets) {
    __shared__ int ls[256];
    int t = threadIdx.x;
    int v = 0;
    for (int k = 0; k < NHB; k++) v += bh_part[k * 256 + t];
    ls[t] = v;
    __syncthreads();
    for (int off = 1; off < 256; off <<= 1) {
        int tv = (t >= off) ? ls[t - off] : 0;
        __syncthreads();
        ls[t] += tv;
        __syncthreads();
    }
    int excl = ls[t] - v;
    if (t < NB) { bstart[t] = excl; bcur[t] = excl; }
    if (t == NB) bstart[NB] = ls[NB - 1];   // = NE
    if (t == 0) offsets[NND] = TOT;
}

// binned scatter: per-block LDS count -> claim contiguous ranges -> dense writes
__global__ __launch_bounds__(256) void passA_kernel(const int* __restrict__ src, const int* __restrict__ dst,
                                                    int* __restrict__ bcur, int2* __restrict__ ebuf, int ne) {
    __shared__ int arr[256];
    int t = threadIdx.x;
    int base = blockIdx.x * CHUNK;
    int lim = min(base + CHUNK, ne);
    arr[t] = 0;
    __syncthreads();
    for (int e = base + t; e < lim; e += 256) atomicAdd(&arr[dst[e] >> 8], 1);
    __syncthreads();
    int cnt_t = arr[t];
    int claimed = 0;
    if (cnt_t > 0) claimed = atomicAdd(&bcur[t], cnt_t);
    __syncthreads();
    arr[t] = claimed;
    __syncthreads();
    for (int e = base + t; e < lim; e += 256) {
        int d = dst[e];
        int pos = atomicAdd(&arr[d >> 8], 1);
        ebuf[pos] = make_int2(src[e], d);
    }
}

// fused: per-bucket degree + local offset scan + dinv + self-loop + edge placement
__global__ __launch_bounds__(256) void bucket_build_kernel(const int2* __restrict__ ebuf, const int* __restrict__ bstart,
                                                           int* __restrict__ offsets, int* __restrict__ csr,
                                                           float* __restrict__ dinv) {
    __shared__ int dcnt[256];
    __shared__ int ls[256];
    __shared__ int cur[256];
    int b = blockIdx.x, t = threadIdx.x;
    dcnt[t] = 0;
    __syncthreads();
    int beg = bstart[b], end = bstart[b + 1];
    for (int p = beg + t; p < end; p += 256) atomicAdd(&dcnt[ebuf[p].y & 255], 1);
    __syncthreads();
    int node = b * 256 + t;
    bool valid = node < NND;
    int d = valid ? (dcnt[t] + 1) : 0;       // +1 self-loop
    ls[t] = d;
    __syncthreads();
    for (int off = 1; off < 256; off <<= 1) {
        int tv = (t >= off) ? ls[t - off] : 0;
        __syncthreads();
        ls[t] += tv;
        __syncthreads();
    }
    int off = bstart[b] + b * 256 + ls[t] - d;   // exclusive
    if (valid) {
        offsets[node] = off;
        dinv[node] = rsqrtf((float)d);
        csr[off] = node;        // self-loop first
        cur[t] = off + 1;
    }
    __syncthreads();
    for (int p = beg + t; p < end; p += 256) {
        int2 ed = ebuf[p];
        int pos = atomicAdd(&cur[ed.y & 255], 1);
        csr[pos] = ed.x;
    }
}

// ---------------- input projection: x0 = relu(x @ W_in + b_in) -> bf16, fused attn layer 0 ----------------
__global__ __launch_bounds__(256) void gemm_in_kernel(const float* __restrict__ x, const float* __restrict__ W,
                                                      const float* __restrict__ b,
                                                      const float* __restrict__ attl, const float* __restrict__ attr,
                                                      __hip_bfloat16* __restrict__ x0bf,
                                                      float* __restrict__ al, float* __restrict__ ar) {
    __shared__ float Wl[INCH * HID];   // 32 KB
    __shared__ float xs[16 * INCH];    // 8 KB
    int t = threadIdx.x;
    for (int i = t; i < INCH * HID; i += 256) Wl[i] = W[i];
    size_t rowbase = (size_t)blockIdx.x * 16;
    for (int i = t; i < 16 * INCH; i += 256) xs[i] = x[rowbase * INCH + i];
    __syncthreads();
    int col = t & 63, rg = t >> 6;
    float a0 = 0.f, a1 = 0.f, a2 = 0.f, a3 = 0.f;
    for (int k = 0; k < INCH; k++) {
        float wk = Wl[k * HID + col];
        a0 = fmaf(xs[(rg * 4 + 0) * INCH + k], wk, a0);
        a1 = fmaf(xs[(rg * 4 + 1) * INCH + k], wk, a1);
        a2 = fmaf(xs[(rg * 4 + 2) * INCH + k], wk, a2);
        a3 = fmaf(xs[(rg * 4 + 3) * INCH + k], wk, a3);
    }
    float bb = b[col];
    a0 = fmaxf(a0 + bb, 0.f); a1 = fmaxf(a1 + bb, 0.f);
    a2 = fmaxf(a2 + bb, 0.f); a3 = fmaxf(a3 + bb, 0.f);
    size_t r = rowbase + rg * 4;
    x0bf[(r + 0) * HID + col] = __float2bfloat16(a0);
    x0bf[(r + 1) * HID + col] = __float2bfloat16(a1);
    x0bf[(r + 2) * HID + col] = __float2bfloat16(a2);
    x0bf[(r + 3) * HID + col] = __float2bfloat16(a3);
    float wl = attl[col], wr = attr[col];
    float p0 = a0 * wl, q0 = a0 * wr, p1 = a1 * wl, q1 = a1 * wr;
    float p2 = a2 * wl, q2 = a2 * wr, p3 = a3 * wl, q3 = a3 * wr;
    for (int off = 32; off > 0; off >>= 1) {
        p0 += __shfl_xor(p0, off); q0 += __shfl_xor(q0, off);
        p1 += __shfl_xor(p1, off); q1 += __shfl_xor(q1, off);
        p2 += __shfl_xor(p2, off); q2 += __shfl_xor(q2, off);
        p3 += __shfl_xor(p3, off); q3 += __shfl_xor(q3, off);
    }
    if (col == 0) {
        al[r + 0] = p0; ar[r + 0] = q0;
        al[r + 1] = p1; ar[r + 1] = q1;
        al[r + 2] = p2; ar[r + 2] = q2;
        al[r + 3] = p3; ar[r + 3] = q3;
    }
}

// ---------------- aggregate: 4 edge-groups x 16 lanes, ushort4 bf16 loads ----------------
__global__ __launch_bounds__(256) void aggregate_kernel(const __hip_bfloat16* __restrict__ hbf,
                                                        const __hip_bfloat16* __restrict__ x0bf,
                                                        const float* __restrict__ al, const float* __restrict__ ar,
                                                        const float* __restrict__ dinv,
                                                        const int* __restrict__ offsets, const int* __restrict__ csr,
                                                        float* __restrict__ y, int n) {
    int v = (blockIdx.x * 256 + threadIdx.x) >> 6;
    int lane = threadIdx.x & 63;
    if (v >= n) return;
    int g = lane >> 4;           // edge subgroup 0..3
    int cl = (lane & 15) << 2;   // channel base (4 channels per lane)
    int beg = offsets[v], end = offsets[v + 1];
    float arv = ar[v];
    float a0 = 0.f, a1 = 0.f, a2 = 0.f, a3 = 0.f;
    for (int base = beg; base < end; base += 64) {
        int p = base + lane;
        int u = 0; float c = 0.f;
        if (p < end) {
            u = csr[p];
            c = tanhf(al[u] + arv) * dinv[u];   // dinv[v] factored out
        }
        int cnt = min(64, end - base);
        int iters = (cnt + 3) >> 2;             // uniform across all lanes
        for (int it = 0; it < iters; ++it) {
            int j = (it << 2) + g;
            int js = (j < cnt) ? j : 0;         // clamp: shfl source always valid+active
            int uj = __shfl(u, js);
            float cj = __shfl(c, js);
            if (j < cnt) {
                ushort4 hv = *(const ushort4*)((const unsigned short*)hbf + (size_t)uj * HID + cl);
                a0 = fmaf(b2f(hv.x), cj, a0);
                a1 = fmaf(b2f(hv.y), cj, a1);
                a2 = fmaf(b2f(hv.z), cj, a2);
                a3 = fmaf(b2f(hv.w), cj, a3);
            }
        }
    }
    a0 += __shfl_xor(a0, 16); a0 += __shfl_xor(a0, 32);
    a1 += __shfl_xor(a1, 16); a1 += __shfl_xor(a1, 32);
    a2 += __shfl_xor(a2, 16); a2 += __shfl_xor(a2, 32);
    a3 += __shfl_xor(a3, 16); a3 += __shfl_xor(a3, 32);
    if (g == 0) {
        float dv = dinv[v];
        ushort4 xb = *(const ushort4*)((const unsigned short*)x0bf + (size_t)v * HID + cl);
        float4 o;
        o.x = fmaxf(fmaf(EPS_RES, b2f(xb.x), a0 * dv), 0.f);
        o.y = fmaxf(fmaf(EPS_RES, b2f(xb.y), a1 * dv), 0.f);
        o.z = fmaxf(fmaf(EPS_RES, b2f(xb.z), a2 * dv), 0.f);
        o.w = fmaxf(fmaf(EPS_RES, b2f(xb.w), a3 * dv), 0.f);
        *(float4*)(y + (size_t)v * HID + cl) = o;
    }
}

// ---------------- batchnorm stats v2: wide grid, float4 lanes, wave-shfl + LDS reduce, partials ----------------
template <int C>
__global__ __launch_bounds__(256) void bn_stats_kernel(const float* __restrict__ y, int rows,
                                                       float* __restrict__ bn_part) {
    const int TPR = C / 4;           // lanes per row (16 for C=64, 8 for C=32)
    const int RPW = 64 / TPR;        // rows per wave per iter
    int lane = threadIdx.x & 63;
    int wave = threadIdx.x >> 6;
    int cl = (lane % TPR) * 4;       // channel base
    int rsub = lane / TPR;
    int rpb = 4 * RPW;               // rows per block iter
    int r = blockIdx.x * rpb + wave * RPW + rsub;
    int stride = gridDim.x * rpb;
    float s0 = 0.f, s1 = 0.f, s2 = 0.f, s3 = 0.f, q0 = 0.f, q1 = 0.f, q2 = 0.f, q3 = 0.f;
    for (; r < rows; r += stride) {
        float4 v = *(const float4*)(y + (size_t)r * C + cl);
        s0 += v.x; q0 = fmaf(v.x, v.x, q0);
        s1 += v.y; q1 = fmaf(v.y, v.y, q1);
        s2 += v.z; q2 = fmaf(v.z, v.z, q2);
        s3 += v.w; q3 = fmaf(v.w, v.w, q3);
    }
    // reduce lanes sharing the same channels (xor partners at multiples of TPR)
    for (int off = TPR; off < 64; off <<= 1) {
        s0 += __shfl_xor(s0, off); q0 += __shfl_xor(q0, off);
        s1 += __shfl_xor(s1, off); q1 += __shfl_xor(q1, off);
        s2 += __shfl_xor(s2, off); q2 += __shfl_xor(q2, off);
        s3 += __shfl_xor(s3, off); q3 += __shfl_xor(q3, off);
    }
    __shared__ float lsum[4][64], lsq[4][64];
    if (lane < TPR) {
        lsum[wave][cl + 0] = s0; lsq[wave][cl + 0] = q0;
        lsum[wave][cl + 1] = s1; lsq[wave][cl + 1] = q1;
        lsum[wave][cl + 2] = s2; lsq[wave][cl + 2] = q2;
        lsum[wave][cl + 3] = s3; lsq[wave][cl + 3] = q3;
    }
    __syncthreads();
    if (threadIdx.x < C) {
        int c = threadIdx.x;
        float ts = lsum[0][c] + lsum[1][c] + lsum[2][c] + lsum[3][c];
        float tq = lsq[0][c] + lsq[1][c] + lsq[2][c] + lsq[3][c];
        bn_part[blockIdx.x * 128 + c] = ts;
        bn_part[blockIdx.x * 128 + 64 + c] = tq;
    }
}

__global__ void bn_finalize_kernel(const float* __restrict__ bn_part, int nblk,
                                   const float* __restrict__ g, const float* __restrict__ b,
                                   float rows_inv, int C, float* __restrict__ scale, float* __restrict__ shift) {
    int c = threadIdx.x;
    if (c >= C) return;
    float s = 0.f, q = 0.f;
    for (int k = 0; k < nblk; k++) { s += bn_part[k * 128 + c]; q += bn_part[k * 128 + 64 + c]; }
    float mean = s * rows_inv;
    float var = q * rows_inv - mean * mean;
    float sc = g[c] * rsqrtf(var + BN_EPS);
    scale[c] = sc;
    shift[c] = b[c] - mean * sc;
}

// BN apply + attention dots for next layer; writes ONLY bf16 h
__global__ __launch_bounds__(256) void bnapply_attn_kernel(const float* __restrict__ y, const float* __restrict__ scale,
                                                           const float* __restrict__ shift,
                                                           const float* __restrict__ attl, const float* __restrict__ attr,
                                                           __hip_bfloat16* __restrict__ hbf,
                                                           float* __restrict__ al, float* __restrict__ ar, int n) {
    int v = (blockIdx.x * 256 + threadIdx.x) >> 6;
    int lane = threadIdx.x & 63;
    if (v >= n) return;
    float val = fmaf(y[(size_t)v * HID + lane], scale[lane], shift[lane]);
    hbf[(size_t)v * HID + lane] = __float2bfloat16(val);
    float pl = val * attl[lane];
    float pr = val * attr[lane];
    for (int off = 32; off > 0; off >>= 1) {
        pl += __shfl_xor(pl, off);
        pr += __shfl_xor(pr, off);
    }
    if (lane == 0) { al[v] = pl; ar[v] = pr; }
}

// ---------------- MLP head ----------------
// z1 = bn(y[:B]) @ W1 + b1   (BN fused into staging)
__global__ __launch_bounds__(256) void mlp1_kernel(const float* __restrict__ y, const float* __restrict__ scale,
                                                   const float* __restrict__ shift, const float* __restrict__ W,
                                                   const float* __restrict__ b, float* __restrict__ z1) {
    __shared__ float Wl[HID * HID];
    __shared__ float xs[16 * HID];
    int t = threadIdx.x;
    for (int i = t; i < HID * HID; i += 256) Wl[i] = W[i];
    size_t rowbase = (size_t)blockIdx.x * 16;
    for (int i = t; i < 16 * HID; i += 256) {
        int c = i & 63;
        xs[i] = fmaf(y[rowbase * HID + i], scale[c], shift[c]);
    }
    __syncthreads();
    int col = t & 63, rg = t >> 6;
    float a0 = 0.f, a1 = 0.f, a2 = 0.f, a3 = 0.f;
    for (int k = 0; k < HID; k++) {
        float wk = Wl[k * HID + col];
        a0 = fmaf(xs[(rg * 4 + 0) * HID + k], wk, a0);
        a1 = fmaf(xs[(rg * 4 + 1) * HID + k], wk, a1);
        a2 = fmaf(xs[(rg * 4 + 2) * HID + k], wk, a2);
        a3 = fmaf(xs[(rg * 4 + 3) * HID + k], wk, a3);
    }
    float bb = b[col];
    size_t r = rowbase + rg * 4;
    z1[(r + 0) * HID + col] = a0 + bb;
    z1[(r + 1) * HID + col] = a1 + bb;
    z1[(r + 2) * HID + col] = a2 + bb;
    z1[(r + 3) * HID + col] = a3 + bb;
}

__global__ __launch_bounds__(256) void mlp2_kernel(const float* __restrict__ z1, const float* __restrict__ scale,
                                                   const float* __restrict__ shift, const float* __restrict__ W,
                                                   const float* __restrict__ b, float* __restrict__ z2) {
    __shared__ float Wl[HID * H2];
    __shared__ float as[16 * HID];
    int t = threadIdx.x;
    for (int i = t; i < HID * H2; i += 256) Wl[i] = W[i];
    size_t rowbase = (size_t)blockIdx.x * 16;
    for (int i = t; i < 16 * HID; i += 256) {
        int c = i & 63;
        float v = z1[rowbase * HID + i];
        as[i] = fmaxf(fmaf(v, scale[c], shift[c]), 0.f);
    }
    __syncthreads();
    int col = t & 31, rg = t >> 5;
    float a0 = 0.f, a1 = 0.f;
    for (int k = 0; k < HID; k++) {
        float wk = Wl[k * H2 + col];
        a0 = fmaf(as[(rg * 2 + 0) * HID + k], wk, a0);
        a1 = fmaf(as[(rg * 2 + 1) * HID + k], wk, a1);
    }
    float bb = b[col];
    size_t r = rowbase + rg * 2;
    z2[(r + 0) * H2 + col] = a0 + bb;
    z2[(r + 1) * H2 + col] = a1 + bb;
}

__global__ __launch_bounds__(256) void mlp3_kernel(const float* __restrict__ z2, const float* __restrict__ scale,
                                                   const float* __restrict__ shift, const float* __restrict__ W3,
                                                   const float* __restrict__ b3, float* __restrict__ out, int rows) {
    int i = blockIdx.x * 256 + threadIdx.x;
    if (i >= rows) return;
    float acc = 0.f;
#pragma unroll
    for (int k = 0; k < H2; k++) {
        float v = fmaxf(fmaf(z2[(size_t)i * H2 + k], scale[k], shift[k]), 0.f);
        acc = fmaf(v, W3[k], acc);
    }
    out[i] = acc + b3[0];
}

// ---------------- launch ----------------
extern "C" void kernel_launch(void* const* d_in, const int* in_sizes, int n_in,
                              void* d_out, int out_size, void* d_ws, size_t ws_size,
                              hipStream_t stream) {
    const float* x     = (const float*)d_in[0];
    const int*   ei    = (const int*)d_in[1];
    const int*   src   = ei;
    const int*   dst   = ei + NE;
    const float* W_in  = (const float*)d_in[3];
    const float* b_in  = (const float*)d_in[4];
    const float* att_l = (const float*)d_in[5];
    const float* att_r = (const float*)d_in[6];
    const float* bn_g  = (const float*)d_in[7];
    const float* bn_b  = (const float*)d_in[8];
    const float* W1    = (const float*)d_in[9];
    const float* b1    = (const float*)d_in[10];
    const float* g1    = (const float*)d_in[11];
    const float* be1   = (const float*)d_in[12];
    const float* W2    = (const float*)d_in[13];
    const float* b2    = (const float*)d_in[14];
    const float* g2    = (const float*)d_in[15];
    const float* be2   = (const float*)d_in[16];
    const float* W3    = (const float*)d_in[17];
    const float* b3    = (const float*)d_in[18];
    float* out = (float*)d_out;

    char* p = (char*)d_ws;
    auto carve = [&](size_t bytes) -> void* {
        void* r = (void*)p;
        p += (bytes + 255) & ~(size_t)255;
        return r;
    };
    int*   bh_part = (int*)carve((size_t)NHB * 256 * 4);
    int*   bstart  = (int*)carve(256 * 4);
    int*   bcur    = (int*)carve(256 * 4);
    int*   offsets = (int*)carve((size_t)(NND + 1) * 4);
    int*   csr     = (int*)carve((size_t)TOT * 4);
    float* dinv    = (float*)carve((size_t)NND * 4);
    float* al      = (float*)carve((size_t)NND * 4);
    float* ar      = (float*)carve((size_t)NND * 4);
    __hip_bfloat16* x0bf = (__hip_bfloat16*)carve((size_t)NND * HID * 2);
    __hip_bfloat16* hbfA = (__hip_bfloat16*)carve((size_t)NND * HID * 2);
    __hip_bfloat16* hbfB = (__hip_bfloat16*)carve((size_t)NND * HID * 2);
    float* ybuf    = (float*)carve((size_t)NND * HID * 4);
    int2*  ebuf    = (int2*)ybuf;   // alias: ebuf (9.6 MB) lifetime ends before ybuf first write
    float* bn_part = (float*)carve((size_t)NSTAT * 128 * 4);
    float* scale   = (float*)carve(64 * 4);
    float* shift   = (float*)carve(64 * 4);
    float* z1      = (float*)carve((size_t)BSZ * HID * 4);
    float* z2      = (float*)carve((size_t)BSZ * H2 * 4);

    const int nblkA = (NE + CHUNK - 1) / CHUNK; // 586

    // --- binned CSR build (4 dispatches, no memsets) ---
    bhist_kernel<<<NHB, 256, 0, stream>>>(dst, bh_part, NE);
    bscan_kernel<<<1, 256, 0, stream>>>(bh_part, bstart, bcur, offsets);
    passA_kernel<<<nblkA, 256, 0, stream>>>(src, dst, bcur, ebuf, NE);
    bucket_build_kernel<<<NB, 256, 0, stream>>>(ebuf, bstart, offsets, csr, dinv);

    // --- input projection (+ attn dots layer 0) ---
    gemm_in_kernel<<<NND / 16, 256, 0, stream>>>(x, W_in, b_in, att_l, att_r, x0bf, al, ar);

    // --- 3 layers ---
    const __hip_bfloat16* h_in = x0bf;
    __hip_bfloat16* hbufs[2] = {hbfA, hbfB};
    for (int l = 0; l < NL; l++) {
        aggregate_kernel<<<NND / 4, 256, 0, stream>>>(h_in, x0bf, al, ar, dinv, offsets, csr, ybuf, NND);
        bn_stats_kernel<64><<<NSTAT, 256, 0, stream>>>(ybuf, NND, bn_part);
        bn_finalize_kernel<<<1, 64, 0, stream>>>(bn_part, NSTAT, bn_g + l * HID, bn_b + l * HID,
                                                 1.0f / NND, HID, scale, shift);
        if (l < NL - 1) {
            bnapply_attn_kernel<<<NND / 4, 256, 0, stream>>>(ybuf, scale, shift,
                                                             att_l + (l + 1) * HID, att_r + (l + 1) * HID,
                                                             hbufs[l], al, ar, NND);
            h_in = hbufs[l];
        }
        // last layer: BN fused into mlp1 staging
    }

    // --- MLP head ---
    mlp1_kernel<<<BSZ / 16, 256, 0, stream>>>(ybuf, scale, shift, W1, b1, z1);
    bn_stats_kernel<64><<<NSTAT, 256, 0, stream>>>(z1, BSZ, bn_part);
    bn_finalize_kernel<<<1, 64, 0, stream>>>(bn_part, NSTAT, g1, be1, 1.0f / BSZ, HID, scale, shift);

    mlp2_kernel<<<BSZ / 16, 256, 0, stream>>>(z1, scale, shift, W2, b2, z2);
    bn_stats_kernel<32><<<NSTAT, 256, 0, stream>>>(z2, BSZ, bn_part);
    bn_finalize_kernel<<<1, 64, 0, stream>>>(bn_part, NSTAT, g2, be2, 1.0f / BSZ, H2, scale, shift);

    mlp3_kernel<<<(BSZ + 255) / 256, 256, 0, stream>>>(z2, scale, shift, W3, b3, out, BSZ);
}

// Round 9
// 449.193 us; speedup vs baseline: 1.4997x; 1.4997x over previous
//
#include <hip/hip_runtime.h>
#include <hip/hip_bf16.h>
#include <math.h>

#define NND 50000
#define NE  1200000
#define TOT (NE + NND)
#define INCH 128
#define HID 64
#define H2  32
#define NL  3
#define BSZ 10000
#define NB  196          // ceil(NND/256) dst-buckets of 256 nodes
#define NHB 128          // bhist partial blocks
#define NSTAT 256        // bn_stats partial blocks
#define CHUNK 2048       // edges per passA block
#define EPS_RES 0.1f
#define BN_EPS 1e-5f

__device__ __forceinline__ float b2f(unsigned short u) {
    return __uint_as_float((unsigned)u << 16);
}

// ---------------- binned CSR build ----------------

// per-block partial bucket histograms (no global atomics, no memset needed)
__global__ __launch_bounds__(256) void bhist_kernel(const int* __restrict__ dst, int* __restrict__ bh_part, int ne) {
    __shared__ int arr[256];
    arr[threadIdx.x] = 0;
    __syncthreads();
    int i = blockIdx.x * 256 + threadIdx.x;
    int stride = gridDim.x * 256;
    for (int e = i; e < ne; e += stride) atomicAdd(&arr[dst[e] >> 8], 1);
    __syncthreads();
    bh_part[blockIdx.x * 256 + threadIdx.x] = arr[threadIdx.x];
}

// reduce partials + exclusive scan -> bstart/bcur; also seeds offsets[NND]
__global__ __launch_bounds__(256) void bscan_kernel(const int* __restrict__ bh_part,
                                                    int* __restrict__ bstart, int* __restrict__ bcur,
                                                    int* __restrict__ offsets) {
    __shared__ int ls[256];
    int t = threadIdx.x;
    int v = 0;
    for (int k = 0; k < NHB; k++) v += bh_part[k * 256 + t];
    ls[t] = v;
    __syncthreads();
    for (int off = 1; off < 256; off <<= 1) {
        int tv = (t >= off) ? ls[t - off] : 0;
        __syncthreads();
        ls[t] += tv;
        __syncthreads();
    }
    int excl = ls[t] - v;
    if (t < NB) { bstart[t] = excl; bcur[t] = excl; }
    if (t == NB) bstart[NB] = ls[NB - 1];   // = NE
    if (t == 0) offsets[NND] = TOT;
}

// binned scatter: per-block LDS count -> claim contiguous ranges -> dense writes
__global__ __launch_bounds__(256) void passA_kernel(const int* __restrict__ src, const int* __restrict__ dst,
                                                    int* __restrict__ bcur, int2* __restrict__ ebuf, int ne) {
    __shared__ int arr[256];
    int t = threadIdx.x;
    int base = blockIdx.x * CHUNK;
    int lim = min(base + CHUNK, ne);
    arr[t] = 0;
    __syncthreads();
    for (int e = base + t; e < lim; e += 256) atomicAdd(&arr[dst[e] >> 8], 1);
    __syncthreads();
    int cnt_t = arr[t];
    int claimed = 0;
    if (cnt_t > 0) claimed = atomicAdd(&bcur[t], cnt_t);
    __syncthreads();
    arr[t] = claimed;
    __syncthreads();
    for (int e = base + t; e < lim; e += 256) {
        int d = dst[e];
        int pos = atomicAdd(&arr[d >> 8], 1);
        ebuf[pos] = make_int2(src[e], d);
    }
}

// fused: per-bucket degree + local offset scan + dinv + self-loop + edge placement
__global__ __launch_bounds__(256) void bucket_build_kernel(const int2* __restrict__ ebuf, const int* __restrict__ bstart,
                                                           int* __restrict__ offsets, int* __restrict__ csr,
                                                           float* __restrict__ dinv) {
    __shared__ int dcnt[256];
    __shared__ int ls[256];
    __shared__ int cur[256];
    int b = blockIdx.x, t = threadIdx.x;
    dcnt[t] = 0;
    __syncthreads();
    int beg = bstart[b], end = bstart[b + 1];
    for (int p = beg + t; p < end; p += 256) atomicAdd(&dcnt[ebuf[p].y & 255], 1);
    __syncthreads();
    int node = b * 256 + t;
    bool valid = node < NND;
    int d = valid ? (dcnt[t] + 1) : 0;       // +1 self-loop
    ls[t] = d;
    __syncthreads();
    for (int off = 1; off < 256; off <<= 1) {
        int tv = (t >= off) ? ls[t - off] : 0;
        __syncthreads();
        ls[t] += tv;
        __syncthreads();
    }
    int off = bstart[b] + b * 256 + ls[t] - d;   // exclusive
    if (valid) {
        offsets[node] = off;
        dinv[node] = rsqrtf((float)d);
        csr[off] = node;        // self-loop first
        cur[t] = off + 1;
    }
    __syncthreads();
    for (int p = beg + t; p < end; p += 256) {
        int2 ed = ebuf[p];
        int pos = atomicAdd(&cur[ed.y & 255], 1);
        csr[pos] = ed.x;
    }
}

// ---------------- input projection: x0 = relu(x @ W_in + b_in) -> bf16, fused attn layer 0 ----------------
__global__ __launch_bounds__(256) void gemm_in_kernel(const float* __restrict__ x, const float* __restrict__ W,
                                                      const float* __restrict__ b,
                                                      const float* __restrict__ attl, const float* __restrict__ attr,
                                                      __hip_bfloat16* __restrict__ x0bf,
                                                      float* __restrict__ al, float* __restrict__ ar) {
    __shared__ float Wl[INCH * HID];   // 32 KB
    __shared__ float xs[16 * INCH];    // 8 KB
    int t = threadIdx.x;
    for (int i = t; i < INCH * HID; i += 256) Wl[i] = W[i];
    size_t rowbase = (size_t)blockIdx.x * 16;
    for (int i = t; i < 16 * INCH; i += 256) xs[i] = x[rowbase * INCH + i];
    __syncthreads();
    int col = t & 63, rg = t >> 6;
    float a0 = 0.f, a1 = 0.f, a2 = 0.f, a3 = 0.f;
    for (int k = 0; k < INCH; k++) {
        float wk = Wl[k * HID + col];
        a0 = fmaf(xs[(rg * 4 + 0) * INCH + k], wk, a0);
        a1 = fmaf(xs[(rg * 4 + 1) * INCH + k], wk, a1);
        a2 = fmaf(xs[(rg * 4 + 2) * INCH + k], wk, a2);
        a3 = fmaf(xs[(rg * 4 + 3) * INCH + k], wk, a3);
    }
    float bb = b[col];
    a0 = fmaxf(a0 + bb, 0.f); a1 = fmaxf(a1 + bb, 0.f);
    a2 = fmaxf(a2 + bb, 0.f); a3 = fmaxf(a3 + bb, 0.f);
    size_t r = rowbase + rg * 4;
    x0bf[(r + 0) * HID + col] = __float2bfloat16(a0);
    x0bf[(r + 1) * HID + col] = __float2bfloat16(a1);
    x0bf[(r + 2) * HID + col] = __float2bfloat16(a2);
    x0bf[(r + 3) * HID + col] = __float2bfloat16(a3);
    float wl = attl[col], wr = attr[col];
    float p0 = a0 * wl, q0 = a0 * wr, p1 = a1 * wl, q1 = a1 * wr;
    float p2 = a2 * wl, q2 = a2 * wr, p3 = a3 * wl, q3 = a3 * wr;
    for (int off = 32; off > 0; off >>= 1) {
        p0 += __shfl_xor(p0, off); q0 += __shfl_xor(q0, off);
        p1 += __shfl_xor(p1, off); q1 += __shfl_xor(q1, off);
        p2 += __shfl_xor(p2, off); q2 += __shfl_xor(q2, off);
        p3 += __shfl_xor(p3, off); q3 += __shfl_xor(q3, off);
    }
    if (col == 0) {
        al[r + 0] = p0; ar[r + 0] = q0;
        al[r + 1] = p1; ar[r + 1] = q1;
        al[r + 2] = p2; ar[r + 2] = q2;
        al[r + 3] = p3; ar[r + 3] = q3;
    }
}

// ---------------- aggregate: 4 edge-groups x 16 lanes, ushort4 bf16 loads ----------------
__global__ __launch_bounds__(256) void aggregate_kernel(const __hip_bfloat16* __restrict__ hbf,
                                                        const __hip_bfloat16* __restrict__ x0bf,
                                                        const float* __restrict__ al, const float* __restrict__ ar,
                                                        const float* __restrict__ dinv,
                                                        const int* __restrict__ offsets, const int* __restrict__ csr,
                                                        float* __restrict__ y, int n) {
    int v = (blockIdx.x * 256 + threadIdx.x) >> 6;
    int lane = threadIdx.x & 63;
    if (v >= n) return;
    int g = lane >> 4;           // edge subgroup 0..3
    int cl = (lane & 15) << 2;   // channel base (4 channels per lane)
    int beg = offsets[v], end = offsets[v + 1];
    float arv = ar[v];
    float a0 = 0.f, a1 = 0.f, a2 = 0.f, a3 = 0.f;
    for (int base = beg; base < end; base += 64) {
        int p = base + lane;
        int u = 0; float c = 0.f;
        if (p < end) {
            u = csr[p];
            c = tanhf(al[u] + arv) * dinv[u];   // dinv[v] factored out
        }
        int cnt = min(64, end - base);
        int iters = (cnt + 3) >> 2;             // uniform across all lanes
        for (int it = 0; it < iters; ++it) {
            int j = (it << 2) + g;
            int js = (j < cnt) ? j : 0;         // clamp: shfl source always valid+active
            int uj = __shfl(u, js);
            float cj = __shfl(c, js);
            if (j < cnt) {
                ushort4 hv = *(const ushort4*)((const unsigned short*)hbf + (size_t)uj * HID + cl);
                a0 = fmaf(b2f(hv.x), cj, a0);
                a1 = fmaf(b2f(hv.y), cj, a1);
                a2 = fmaf(b2f(hv.z), cj, a2);
                a3 = fmaf(b2f(hv.w), cj, a3);
            }
        }
    }
    a0 += __shfl_xor(a0, 16); a0 += __shfl_xor(a0, 32);
    a1 += __shfl_xor(a1, 16); a1 += __shfl_xor(a1, 32);
    a2 += __shfl_xor(a2, 16); a2 += __shfl_xor(a2, 32);
    a3 += __shfl_xor(a3, 16); a3 += __shfl_xor(a3, 32);
    if (g == 0) {
        float dv = dinv[v];
        ushort4 xb = *(const ushort4*)((const unsigned short*)x0bf + (size_t)v * HID + cl);
        float4 o;
        o.x = fmaxf(fmaf(EPS_RES, b2f(xb.x), a0 * dv), 0.f);
        o.y = fmaxf(fmaf(EPS_RES, b2f(xb.y), a1 * dv), 0.f);
        o.z = fmaxf(fmaf(EPS_RES, b2f(xb.z), a2 * dv), 0.f);
        o.w = fmaxf(fmaf(EPS_RES, b2f(xb.w), a3 * dv), 0.f);
        *(float4*)(y + (size_t)v * HID + cl) = o;
    }
}

// ---------------- batchnorm stats: wide grid, float4 lanes, wave-shfl + LDS reduce, partials ----------------
template <int C>
__global__ __launch_bounds__(256) void bn_stats_kernel(const float* __restrict__ y, int rows,
                                                       float* __restrict__ bn_part) {
    const int TPR = C / 4;           // lanes per row (16 for C=64, 8 for C=32)
    const int RPW = 64 / TPR;        // rows per wave per iter
    int lane = threadIdx.x & 63;
    int wave = threadIdx.x >> 6;
    int cl = (lane % TPR) * 4;       // channel base
    int rsub = lane / TPR;
    int rpb = 4 * RPW;               // rows per block iter
    int r = blockIdx.x * rpb + wave * RPW + rsub;
    int stride = gridDim.x * rpb;
    float s0 = 0.f, s1 = 0.f, s2 = 0.f, s3 = 0.f, q0 = 0.f, q1 = 0.f, q2 = 0.f, q3 = 0.f;
    for (; r < rows; r += stride) {
        float4 v = *(const float4*)(y + (size_t)r * C + cl);
        s0 += v.x; q0 = fmaf(v.x, v.x, q0);
        s1 += v.y; q1 = fmaf(v.y, v.y, q1);
        s2 += v.z; q2 = fmaf(v.z, v.z, q2);
        s3 += v.w; q3 = fmaf(v.w, v.w, q3);
    }
    // reduce lanes sharing the same channels (xor partners at multiples of TPR)
    for (int off = TPR; off < 64; off <<= 1) {
        s0 += __shfl_xor(s0, off); q0 += __shfl_xor(q0, off);
        s1 += __shfl_xor(s1, off); q1 += __shfl_xor(q1, off);
        s2 += __shfl_xor(s2, off); q2 += __shfl_xor(q2, off);
        s3 += __shfl_xor(s3, off); q3 += __shfl_xor(q3, off);
    }
    __shared__ float lsum[4][64], lsq[4][64];
    if (lane < TPR) {
        lsum[wave][cl + 0] = s0; lsq[wave][cl + 0] = q0;
        lsum[wave][cl + 1] = s1; lsq[wave][cl + 1] = q1;
        lsum[wave][cl + 2] = s2; lsq[wave][cl + 2] = q2;
        lsum[wave][cl + 3] = s3; lsq[wave][cl + 3] = q3;
    }
    __syncthreads();
    if (threadIdx.x < C) {
        int c = threadIdx.x;
        float ts = lsum[0][c] + lsum[1][c] + lsum[2][c] + lsum[3][c];
        float tq = lsq[0][c] + lsq[1][c] + lsq[2][c] + lsq[3][c];
        bn_part[blockIdx.x * 128 + c] = ts;
        bn_part[blockIdx.x * 128 + 64 + c] = tq;
    }
}

// ---------------- batchnorm finalize v2: 256 threads = 64 channels x 4 k-groups ----------------
// R8 post-mortem: single-wave loop over 256 partials was 64 µs (serial latency).
// Now: thread (c, kg) sums k = kg, kg+4, ... (64 strided independent loads), LDS-reduce 4 groups.
__global__ __launch_bounds__(256) void bn_finalize_kernel(const float* __restrict__ bn_part, int nblk,
                                                          const float* __restrict__ g, const float* __restrict__ b,
                                                          float rows_inv, int C,
                                                          float* __restrict__ scale, float* __restrict__ shift) {
    int t = threadIdx.x;
    int c = t & 63;
    int kg = t >> 6;
    float s = 0.f, q = 0.f;
    for (int k = kg; k < nblk; k += 4) {
        s += bn_part[k * 128 + c];
        q += bn_part[k * 128 + 64 + c];
    }
    __shared__ float lsum[4][64], lsq[4][64];
    lsum[kg][c] = s;
    lsq[kg][c] = q;
    __syncthreads();
    if (t < C) {
        float ts = lsum[0][t] + lsum[1][t] + lsum[2][t] + lsum[3][t];
        float tq = lsq[0][t] + lsq[1][t] + lsq[2][t] + lsq[3][t];
        float mean = ts * rows_inv;
        float var = tq * rows_inv - mean * mean;
        float sc = g[t] * rsqrtf(var + BN_EPS);
        scale[t] = sc;
        shift[t] = b[t] - mean * sc;
    }
}

// BN apply + attention dots for next layer; writes ONLY bf16 h
__global__ __launch_bounds__(256) void bnapply_attn_kernel(const float* __restrict__ y, const float* __restrict__ scale,
                                                           const float* __restrict__ shift,
                                                           const float* __restrict__ attl, const float* __restrict__ attr,
                                                           __hip_bfloat16* __restrict__ hbf,
                                                           float* __restrict__ al, float* __restrict__ ar, int n) {
    int v = (blockIdx.x * 256 + threadIdx.x) >> 6;
    int lane = threadIdx.x & 63;
    if (v >= n) return;
    float val = fmaf(y[(size_t)v * HID + lane], scale[lane], shift[lane]);
    hbf[(size_t)v * HID + lane] = __float2bfloat16(val);
    float pl = val * attl[lane];
    float pr = val * attr[lane];
    for (int off = 32; off > 0; off >>= 1) {
        pl += __shfl_xor(pl, off);
        pr += __shfl_xor(pr, off);
    }
    if (lane == 0) { al[v] = pl; ar[v] = pr; }
}

// ---------------- MLP head ----------------
// z1 = bn(y[:B]) @ W1 + b1   (BN fused into staging)
__global__ __launch_bounds__(256) void mlp1_kernel(const float* __restrict__ y, const float* __restrict__ scale,
                                                   const float* __restrict__ shift, const float* __restrict__ W,
                                                   const float* __restrict__ b, float* __restrict__ z1) {
    __shared__ float Wl[HID * HID];
    __shared__ float xs[16 * HID];
    int t = threadIdx.x;
    for (int i = t; i < HID * HID; i += 256) Wl[i] = W[i];
    size_t rowbase = (size_t)blockIdx.x * 16;
    for (int i = t; i < 16 * HID; i += 256) {
        int c = i & 63;
        xs[i] = fmaf(y[rowbase * HID + i], scale[c], shift[c]);
    }
    __syncthreads();
    int col = t & 63, rg = t >> 6;
    float a0 = 0.f, a1 = 0.f, a2 = 0.f, a3 = 0.f;
    for (int k = 0; k < HID; k++) {
        float wk = Wl[k * HID + col];
        a0 = fmaf(xs[(rg * 4 + 0) * HID + k], wk, a0);
        a1 = fmaf(xs[(rg * 4 + 1) * HID + k], wk, a1);
        a2 = fmaf(xs[(rg * 4 + 2) * HID + k], wk, a2);
        a3 = fmaf(xs[(rg * 4 + 3) * HID + k], wk, a3);
    }
    float bb = b[col];
    size_t r = rowbase + rg * 4;
    z1[(r + 0) * HID + col] = a0 + bb;
    z1[(r + 1) * HID + col] = a1 + bb;
    z1[(r + 2) * HID + col] = a2 + bb;
    z1[(r + 3) * HID + col] = a3 + bb;
}

__global__ __launch_bounds__(256) void mlp2_kernel(const float* __restrict__ z1, const float* __restrict__ scale,
                                                   const float* __restrict__ shift, const float* __restrict__ W,
                                                   const float* __restrict__ b, float* __restrict__ z2) {
    __shared__ float Wl[HID * H2];
    __shared__ float as[16 * HID];
    int t = threadIdx.x;
    for (int i = t; i < HID * H2; i += 256) Wl[i] = W[i];
    size_t rowbase = (size_t)blockIdx.x * 16;
    for (int i = t; i < 16 * HID; i += 256) {
        int c = i & 63;
        float v = z1[rowbase * HID + i];
        as[i] = fmaxf(fmaf(v, scale[c], shift[c]), 0.f);
    }
    __syncthreads();
    int col = t & 31, rg = t >> 5;
    float a0 = 0.f, a1 = 0.f;
    for (int k = 0; k < HID; k++) {
        float wk = Wl[k * H2 + col];
        a0 = fmaf(as[(rg * 2 + 0) * HID + k], wk, a0);
        a1 = fmaf(as[(rg * 2 + 1) * HID + k], wk, a1);
    }
    float bb = b[col];
    size_t r = rowbase + rg * 2;
    z2[(r + 0) * H2 + col] = a0 + bb;
    z2[(r + 1) * H2 + col] = a1 + bb;
}

__global__ __launch_bounds__(256) void mlp3_kernel(const float* __restrict__ z2, const float* __restrict__ scale,
                                                   const float* __restrict__ shift, const float* __restrict__ W3,
                                                   const float* __restrict__ b3, float* __restrict__ out, int rows) {
    int i = blockIdx.x * 256 + threadIdx.x;
    if (i >= rows) return;
    float acc = 0.f;
#pragma unroll
    for (int k = 0; k < H2; k++) {
        float v = fmaxf(fmaf(z2[(size_t)i * H2 + k], scale[k], shift[k]), 0.f);
        acc = fmaf(v, W3[k], acc);
    }
    out[i] = acc + b3[0];
}

// ---------------- launch ----------------
extern "C" void kernel_launch(void* const* d_in, const int* in_sizes, int n_in,
                              void* d_out, int out_size, void* d_ws, size_t ws_size,
                              hipStream_t stream) {
    const float* x     = (const float*)d_in[0];
    const int*   ei    = (const int*)d_in[1];
    const int*   src   = ei;
    const int*   dst   = ei + NE;
    const float* W_in  = (const float*)d_in[3];
    const float* b_in  = (const float*)d_in[4];
    const float* att_l = (const float*)d_in[5];
    const float* att_r = (const float*)d_in[6];
    const float* bn_g  = (const float*)d_in[7];
    const float* bn_b  = (const float*)d_in[8];
    const float* W1    = (const float*)d_in[9];
    const float* b1    = (const float*)d_in[10];
    const float* g1    = (const float*)d_in[11];
    const float* be1   = (const float*)d_in[12];
    const float* W2    = (const float*)d_in[13];
    const float* b2    = (const float*)d_in[14];
    const float* g2    = (const float*)d_in[15];
    const float* be2   = (const float*)d_in[16];
    const float* W3    = (const float*)d_in[17];
    const float* b3    = (const float*)d_in[18];
    float* out = (float*)d_out;

    char* p = (char*)d_ws;
    auto carve = [&](size_t bytes) -> void* {
        void* r = (void*)p;
        p += (bytes + 255) & ~(size_t)255;
        return r;
    };
    int*   bh_part = (int*)carve((size_t)NHB * 256 * 4);
    int*   bstart  = (int*)carve(256 * 4);
    int*   bcur    = (int*)carve(256 * 4);
    int*   offsets = (int*)carve((size_t)(NND + 1) * 4);
    int*   csr     = (int*)carve((size_t)TOT * 4);
    float* dinv    = (float*)carve((size_t)NND * 4);
    float* al      = (float*)carve((size_t)NND * 4);
    float* ar      = (float*)carve((size_t)NND * 4);
    __hip_bfloat16* x0bf = (__hip_bfloat16*)carve((size_t)NND * HID * 2);
    __hip_bfloat16* hbfA = (__hip_bfloat16*)carve((size_t)NND * HID * 2);
    __hip_bfloat16* hbfB = (__hip_bfloat16*)carve((size_t)NND * HID * 2);
    float* ybuf    = (float*)carve((size_t)NND * HID * 4);
    int2*  ebuf    = (int2*)ybuf;   // alias: ebuf (9.6 MB) lifetime ends before ybuf first write
    float* bn_part = (float*)carve((size_t)NSTAT * 128 * 4);
    float* scale   = (float*)carve(64 * 4);
    float* shift   = (float*)carve(64 * 4);
    float* z1      = (float*)carve((size_t)BSZ * HID * 4);
    float* z2      = (float*)carve((size_t)BSZ * H2 * 4);

    const int nblkA = (NE + CHUNK - 1) / CHUNK; // 586

    // --- binned CSR build (4 dispatches, no memsets) ---
    bhist_kernel<<<NHB, 256, 0, stream>>>(dst, bh_part, NE);
    bscan_kernel<<<1, 256, 0, stream>>>(bh_part, bstart, bcur, offsets);
    passA_kernel<<<nblkA, 256, 0, stream>>>(src, dst, bcur, ebuf, NE);
    bucket_build_kernel<<<NB, 256, 0, stream>>>(ebuf, bstart, offsets, csr, dinv);

    // --- input projection (+ attn dots layer 0) ---
    gemm_in_kernel<<<NND / 16, 256, 0, stream>>>(x, W_in, b_in, att_l, att_r, x0bf, al, ar);

    // --- 3 layers ---
    const __hip_bfloat16* h_in = x0bf;
    __hip_bfloat16* hbufs[2] = {hbfA, hbfB};
    for (int l = 0; l < NL; l++) {
        aggregate_kernel<<<NND / 4, 256, 0, stream>>>(h_in, x0bf, al, ar, dinv, offsets, csr, ybuf, NND);
        bn_stats_kernel<64><<<NSTAT, 256, 0, stream>>>(ybuf, NND, bn_part);
        bn_finalize_kernel<<<1, 256, 0, stream>>>(bn_part, NSTAT, bn_g + l * HID, bn_b + l * HID,
                                                  1.0f / NND, HID, scale, shift);
        if (l < NL - 1) {
            bnapply_attn_kernel<<<NND / 4, 256, 0, stream>>>(ybuf, scale, shift,
                                                             att_l + (l + 1) * HID, att_r + (l + 1) * HID,
                                                             hbufs[l], al, ar, NND);
            h_in = hbufs[l];
        }
        // last layer: BN fused into mlp1 staging
    }

    // --- MLP head ---
    mlp1_kernel<<<BSZ / 16, 256, 0, stream>>>(ybuf, scale, shift, W1, b1, z1);
    bn_stats_kernel<64><<<NSTAT, 256, 0, stream>>>(z1, BSZ, bn_part);
    bn_finalize_kernel<<<1, 256, 0, stream>>>(bn_part, NSTAT, g1, be1, 1.0f / BSZ, HID, scale, shift);

    mlp2_kernel<<<BSZ / 16, 256, 0, stream>>>(z1, scale, shift, W2, b2, z2);
    bn_stats_kernel<32><<<NSTAT, 256, 0, stream>>>(z2, BSZ, bn_part);
    bn_finalize_kernel<<<1, 256, 0, stream>>>(bn_part, NSTAT, g2, be2, 1.0f / BSZ, H2, scale, shift);

    mlp3_kernel<<<(BSZ + 255) / 256, 256, 0, stream>>>(z2, scale, shift, W3, b3, out, BSZ);
}

// Round 10
// 434.210 us; speedup vs baseline: 1.5514x; 1.0345x over previous
//
#include <hip/hip_runtime.h>
#include <hip/hip_bf16.h>
#include <math.h>

#define NND 50000
#define NE  1200000
#define TOT (NE + NND)
#define INCH 128
#define HID 64
#define H2  32
#define NL  3
#define BSZ 10000
#define NB  196          // ceil(NND/256) dst-buckets of 256 nodes
#define NHB 128          // bhist partial blocks
#define NSTAT 256        // bn_stats partial blocks
#define CHUNK 4096       // edges per passA block (bigger -> denser per-bucket write runs)
#define EPS_RES 0.1f
#define BN_EPS 1e-5f

typedef unsigned short ushort8v __attribute__((ext_vector_type(8)));

__device__ __forceinline__ float b2f(unsigned short u) {
    return __uint_as_float((unsigned)u << 16);
}

// ---------------- binned CSR build ----------------

// per-block partial bucket histograms (no global atomics, no memset needed)
__global__ __launch_bounds__(256) void bhist_kernel(const int* __restrict__ dst, int* __restrict__ bh_part, int ne) {
    __shared__ int arr[256];
    arr[threadIdx.x] = 0;
    __syncthreads();
    int i = blockIdx.x * 256 + threadIdx.x;
    int stride = gridDim.x * 256;
    for (int e = i; e < ne; e += stride) atomicAdd(&arr[dst[e] >> 8], 1);
    __syncthreads();
    bh_part[blockIdx.x * 256 + threadIdx.x] = arr[threadIdx.x];
}

// reduce partials + exclusive scan -> bstart/bcur; also seeds offsets[NND]
__global__ __launch_bounds__(256) void bscan_kernel(const int* __restrict__ bh_part,
                                                    int* __restrict__ bstart, int* __restrict__ bcur,
                                                    int* __restrict__ offsets) {
    __shared__ int ls[256];
    int t = threadIdx.x;
    int v = 0;
    for (int k = 0; k < NHB; k++) v += bh_part[k * 256 + t];
    ls[t] = v;
    __syncthreads();
    for (int off = 1; off < 256; off <<= 1) {
        int tv = (t >= off) ? ls[t - off] : 0;
        __syncthreads();
        ls[t] += tv;
        __syncthreads();
    }
    int excl = ls[t] - v;
    if (t < NB) { bstart[t] = excl; bcur[t] = excl; }
    if (t == NB) bstart[NB] = ls[NB - 1];   // = NE
    if (t == 0) offsets[NND] = TOT;
}

// binned scatter: per-block LDS count -> claim contiguous ranges -> dense writes
__global__ __launch_bounds__(256) void passA_kernel(const int* __restrict__ src, const int* __restrict__ dst,
                                                    int* __restrict__ bcur, int2* __restrict__ ebuf, int ne) {
    __shared__ int arr[256];
    int t = threadIdx.x;
    int base = blockIdx.x * CHUNK;
    int lim = min(base + CHUNK, ne);
    arr[t] = 0;
    __syncthreads();
    for (int e = base + t; e < lim; e += 256) atomicAdd(&arr[dst[e] >> 8], 1);
    __syncthreads();
    int cnt_t = arr[t];
    int claimed = 0;
    if (cnt_t > 0) claimed = atomicAdd(&bcur[t], cnt_t);
    __syncthreads();
    arr[t] = claimed;
    __syncthreads();
    for (int e = base + t; e < lim; e += 256) {
        int d = dst[e];
        int pos = atomicAdd(&arr[d >> 8], 1);
        ebuf[pos] = make_int2(src[e], d);
    }
}

// fused: per-bucket degree + local offset scan + dinv + self-loop + edge placement
__global__ __launch_bounds__(256) void bucket_build_kernel(const int2* __restrict__ ebuf, const int* __restrict__ bstart,
                                                           int* __restrict__ offsets, int* __restrict__ csr,
                                                           float* __restrict__ dinv) {
    __shared__ int dcnt[256];
    __shared__ int ls[256];
    __shared__ int cur[256];
    int b = blockIdx.x, t = threadIdx.x;
    dcnt[t] = 0;
    __syncthreads();
    int beg = bstart[b], end = bstart[b + 1];
    for (int p = beg + t; p < end; p += 256) atomicAdd(&dcnt[ebuf[p].y & 255], 1);
    __syncthreads();
    int node = b * 256 + t;
    bool valid = node < NND;
    int d = valid ? (dcnt[t] + 1) : 0;       // +1 self-loop
    ls[t] = d;
    __syncthreads();
    for (int off = 1; off < 256; off <<= 1) {
        int tv = (t >= off) ? ls[t - off] : 0;
        __syncthreads();
        ls[t] += tv;
        __syncthreads();
    }
    int off = bstart[b] + b * 256 + ls[t] - d;   // exclusive
    if (valid) {
        offsets[node] = off;
        dinv[node] = rsqrtf((float)d);
        csr[off] = node;        // self-loop first
        cur[t] = off + 1;
    }
    __syncthreads();
    for (int p = beg + t; p < end; p += 256) {
        int2 ed = ebuf[p];
        int pos = atomicAdd(&cur[ed.y & 255], 1);
        csr[pos] = ed.x;
    }
}

// ---------------- input projection: x0 = relu(x @ W_in + b_in) -> bf16, fused attn layer 0 ----------------
__global__ __launch_bounds__(256) void gemm_in_kernel(const float* __restrict__ x, const float* __restrict__ W,
                                                      const float* __restrict__ b,
                                                      const float* __restrict__ attl, const float* __restrict__ attr,
                                                      __hip_bfloat16* __restrict__ x0bf,
                                                      float* __restrict__ al, float* __restrict__ ar) {
    __shared__ float Wl[INCH * HID];   // 32 KB
    __shared__ float xs[16 * INCH];    // 8 KB
    int t = threadIdx.x;
    for (int i = t; i < INCH * HID; i += 256) Wl[i] = W[i];
    size_t rowbase = (size_t)blockIdx.x * 16;
    for (int i = t; i < 16 * INCH; i += 256) xs[i] = x[rowbase * INCH + i];
    __syncthreads();
    int col = t & 63, rg = t >> 6;
    float a0 = 0.f, a1 = 0.f, a2 = 0.f, a3 = 0.f;
    for (int k = 0; k < INCH; k++) {
        float wk = Wl[k * HID + col];
        a0 = fmaf(xs[(rg * 4 + 0) * INCH + k], wk, a0);
        a1 = fmaf(xs[(rg * 4 + 1) * INCH + k], wk, a1);
        a2 = fmaf(xs[(rg * 4 + 2) * INCH + k], wk, a2);
        a3 = fmaf(xs[(rg * 4 + 3) * INCH + k], wk, a3);
    }
    float bb = b[col];
    a0 = fmaxf(a0 + bb, 0.f); a1 = fmaxf(a1 + bb, 0.f);
    a2 = fmaxf(a2 + bb, 0.f); a3 = fmaxf(a3 + bb, 0.f);
    size_t r = rowbase + rg * 4;
    x0bf[(r + 0) * HID + col] = __float2bfloat16(a0);
    x0bf[(r + 1) * HID + col] = __float2bfloat16(a1);
    x0bf[(r + 2) * HID + col] = __float2bfloat16(a2);
    x0bf[(r + 3) * HID + col] = __float2bfloat16(a3);
    float wl = attl[col], wr = attr[col];
    float p0 = a0 * wl, q0 = a0 * wr, p1 = a1 * wl, q1 = a1 * wr;
    float p2 = a2 * wl, q2 = a2 * wr, p3 = a3 * wl, q3 = a3 * wr;
    for (int off = 32; off > 0; off >>= 1) {
        p0 += __shfl_xor(p0, off); q0 += __shfl_xor(q0, off);
        p1 += __shfl_xor(p1, off); q1 += __shfl_xor(q1, off);
        p2 += __shfl_xor(p2, off); q2 += __shfl_xor(q2, off);
        p3 += __shfl_xor(p3, off); q3 += __shfl_xor(q3, off);
    }
    if (col == 0) {
        al[r + 0] = p0; ar[r + 0] = q0;
        al[r + 1] = p1; ar[r + 1] = q1;
        al[r + 2] = p2; ar[r + 2] = q2;
        al[r + 3] = p3; ar[r + 3] = q3;
    }
}

// ---------------- aggregate v3: 8 edge-groups x 8 lanes, ushort8 (16B) bf16 loads ----------------
// wave-uniform iteration count; __shfl executed unconditionally (clamped index) by all 64 lanes
__global__ __launch_bounds__(256) void aggregate_kernel(const __hip_bfloat16* __restrict__ hbf,
                                                        const __hip_bfloat16* __restrict__ x0bf,
                                                        const float* __restrict__ al, const float* __restrict__ ar,
                                                        const float* __restrict__ dinv,
                                                        const int* __restrict__ offsets, const int* __restrict__ csr,
                                                        float* __restrict__ y, int n) {
    int v = (blockIdx.x * 256 + threadIdx.x) >> 6;
    int lane = threadIdx.x & 63;
    if (v >= n) return;
    int g = lane >> 3;           // edge subgroup 0..7
    int cl = (lane & 7) << 3;    // channel base (8 channels per lane)
    int beg = offsets[v], end = offsets[v + 1];
    float arv = ar[v];
    float a0 = 0.f, a1 = 0.f, a2 = 0.f, a3 = 0.f, a4 = 0.f, a5 = 0.f, a6 = 0.f, a7 = 0.f;
    for (int base = beg; base < end; base += 64) {
        int p = base + lane;
        int u = 0; float c = 0.f;
        if (p < end) {
            u = csr[p];
            c = tanhf(al[u] + arv) * dinv[u];   // dinv[v] factored out
        }
        int cnt = min(64, end - base);
        int iters = (cnt + 7) >> 3;             // uniform across all lanes
        for (int it = 0; it < iters; ++it) {
            int j = (it << 3) + g;
            int js = (j < cnt) ? j : 0;         // clamp: shfl source always valid+active
            int uj = __shfl(u, js);
            float cj = __shfl(c, js);
            if (j < cnt) {
                ushort8v hv = *(const ushort8v*)((const unsigned short*)hbf + (size_t)uj * HID + cl);
                a0 = fmaf(b2f(hv[0]), cj, a0);
                a1 = fmaf(b2f(hv[1]), cj, a1);
                a2 = fmaf(b2f(hv[2]), cj, a2);
                a3 = fmaf(b2f(hv[3]), cj, a3);
                a4 = fmaf(b2f(hv[4]), cj, a4);
                a5 = fmaf(b2f(hv[5]), cj, a5);
                a6 = fmaf(b2f(hv[6]), cj, a6);
                a7 = fmaf(b2f(hv[7]), cj, a7);
            }
        }
    }
    // reduce the 8 edge subgroups (xor partners at 8,16,32)
    for (int off = 8; off < 64; off <<= 1) {
        a0 += __shfl_xor(a0, off); a1 += __shfl_xor(a1, off);
        a2 += __shfl_xor(a2, off); a3 += __shfl_xor(a3, off);
        a4 += __shfl_xor(a4, off); a5 += __shfl_xor(a5, off);
        a6 += __shfl_xor(a6, off); a7 += __shfl_xor(a7, off);
    }
    if (g == 0) {
        float dv = dinv[v];
        ushort8v xb = *(const ushort8v*)((const unsigned short*)x0bf + (size_t)v * HID + cl);
        float4 o0, o1;
        o0.x = fmaxf(fmaf(EPS_RES, b2f(xb[0]), a0 * dv), 0.f);
        o0.y = fmaxf(fmaf(EPS_RES, b2f(xb[1]), a1 * dv), 0.f);
        o0.z = fmaxf(fmaf(EPS_RES, b2f(xb[2]), a2 * dv), 0.f);
        o0.w = fmaxf(fmaf(EPS_RES, b2f(xb[3]), a3 * dv), 0.f);
        o1.x = fmaxf(fmaf(EPS_RES, b2f(xb[4]), a4 * dv), 0.f);
        o1.y = fmaxf(fmaf(EPS_RES, b2f(xb[5]), a5 * dv), 0.f);
        o1.z = fmaxf(fmaf(EPS_RES, b2f(xb[6]), a6 * dv), 0.f);
        o1.w = fmaxf(fmaf(EPS_RES, b2f(xb[7]), a7 * dv), 0.f);
        *(float4*)(y + (size_t)v * HID + cl) = o0;
        *(float4*)(y + (size_t)v * HID + cl + 4) = o1;
    }
}

// ---------------- batchnorm stats: wide grid, float4 lanes, wave-shfl + LDS reduce, partials ----------------
template <int C>
__global__ __launch_bounds__(256) void bn_stats_kernel(const float* __restrict__ y, int rows,
                                                       float* __restrict__ bn_part) {
    const int TPR = C / 4;           // lanes per row (16 for C=64, 8 for C=32)
    const int RPW = 64 / TPR;        // rows per wave per iter
    int lane = threadIdx.x & 63;
    int wave = threadIdx.x >> 6;
    int cl = (lane % TPR) * 4;       // channel base
    int rsub = lane / TPR;
    int rpb = 4 * RPW;               // rows per block iter
    int r = blockIdx.x * rpb + wave * RPW + rsub;
    int stride = gridDim.x * rpb;
    float s0 = 0.f, s1 = 0.f, s2 = 0.f, s3 = 0.f, q0 = 0.f, q1 = 0.f, q2 = 0.f, q3 = 0.f;
    for (; r < rows; r += stride) {
        float4 v = *(const float4*)(y + (size_t)r * C + cl);
        s0 += v.x; q0 = fmaf(v.x, v.x, q0);
        s1 += v.y; q1 = fmaf(v.y, v.y, q1);
        s2 += v.z; q2 = fmaf(v.z, v.z, q2);
        s3 += v.w; q3 = fmaf(v.w, v.w, q3);
    }
    for (int off = TPR; off < 64; off <<= 1) {
        s0 += __shfl_xor(s0, off); q0 += __shfl_xor(q0, off);
        s1 += __shfl_xor(s1, off); q1 += __shfl_xor(q1, off);
        s2 += __shfl_xor(s2, off); q2 += __shfl_xor(q2, off);
        s3 += __shfl_xor(s3, off); q3 += __shfl_xor(q3, off);
    }
    __shared__ float lsum[4][64], lsq[4][64];
    if (lane < TPR) {
        lsum[wave][cl + 0] = s0; lsq[wave][cl + 0] = q0;
        lsum[wave][cl + 1] = s1; lsq[wave][cl + 1] = q1;
        lsum[wave][cl + 2] = s2; lsq[wave][cl + 2] = q2;
        lsum[wave][cl + 3] = s3; lsq[wave][cl + 3] = q3;
    }
    __syncthreads();
    if (threadIdx.x < C) {
        int c = threadIdx.x;
        float ts = lsum[0][c] + lsum[1][c] + lsum[2][c] + lsum[3][c];
        float tq = lsq[0][c] + lsq[1][c] + lsq[2][c] + lsq[3][c];
        bn_part[blockIdx.x * 128 + c] = ts;
        bn_part[blockIdx.x * 128 + 64 + c] = tq;
    }
}

// ---------------- batchnorm finalize: 256 threads = 64 channels x 4 k-groups ----------------
__global__ __launch_bounds__(256) void bn_finalize_kernel(const float* __restrict__ bn_part, int nblk,
                                                          const float* __restrict__ g, const float* __restrict__ b,
                                                          float rows_inv, int C,
                                                          float* __restrict__ scale, float* __restrict__ shift) {
    int t = threadIdx.x;
    int c = t & 63;
    int kg = t >> 6;
    float s = 0.f, q = 0.f;
    for (int k = kg; k < nblk; k += 4) {
        s += bn_part[k * 128 + c];
        q += bn_part[k * 128 + 64 + c];
    }
    __shared__ float lsum[4][64], lsq[4][64];
    lsum[kg][c] = s;
    lsq[kg][c] = q;
    __syncthreads();
    if (t < C) {
        float ts = lsum[0][t] + lsum[1][t] + lsum[2][t] + lsum[3][t];
        float tq = lsq[0][t] + lsq[1][t] + lsq[2][t] + lsq[3][t];
        float mean = ts * rows_inv;
        float var = tq * rows_inv - mean * mean;
        float sc = g[t] * rsqrtf(var + BN_EPS);
        scale[t] = sc;
        shift[t] = b[t] - mean * sc;
    }
}

// BN apply + attention dots for next layer; writes ONLY bf16 h
__global__ __launch_bounds__(256) void bnapply_attn_kernel(const float* __restrict__ y, const float* __restrict__ scale,
                                                           const float* __restrict__ shift,
                                                           const float* __restrict__ attl, const float* __restrict__ attr,
                                                           __hip_bfloat16* __restrict__ hbf,
                                                           float* __restrict__ al, float* __restrict__ ar, int n) {
    int v = (blockIdx.x * 256 + threadIdx.x) >> 6;
    int lane = threadIdx.x & 63;
    if (v >= n) return;
    float val = fmaf(y[(size_t)v * HID + lane], scale[lane], shift[lane]);
    hbf[(size_t)v * HID + lane] = __float2bfloat16(val);
    float pl = val * attl[lane];
    float pr = val * attr[lane];
    for (int off = 32; off > 0; off >>= 1) {
        pl += __shfl_xor(pl, off);
        pr += __shfl_xor(pr, off);
    }
    if (lane == 0) { al[v] = pl; ar[v] = pr; }
}

// ---------------- MLP head ----------------
// z1 = bn(y[:B]) @ W1 + b1   (BN fused into staging)
__global__ __launch_bounds__(256) void mlp1_kernel(const float* __restrict__ y, const float* __restrict__ scale,
                                                   const float* __restrict__ shift, const float* __restrict__ W,
                                                   const float* __restrict__ b, float* __restrict__ z1) {
    __shared__ float Wl[HID * HID];
    __shared__ float xs[16 * HID];
    int t = threadIdx.x;
    for (int i = t; i < HID * HID; i += 256) Wl[i] = W[i];
    size_t rowbase = (size_t)blockIdx.x * 16;
    for (int i = t; i < 16 * HID; i += 256) {
        int c = i & 63;
        xs[i] = fmaf(y[rowbase * HID + i], scale[c], shift[c]);
    }
    __syncthreads();
    int col = t & 63, rg = t >> 6;
    float a0 = 0.f, a1 = 0.f, a2 = 0.f, a3 = 0.f;
    for (int k = 0; k < HID; k++) {
        float wk = Wl[k * HID + col];
        a0 = fmaf(xs[(rg * 4 + 0) * HID + k], wk, a0);
        a1 = fmaf(xs[(rg * 4 + 1) * HID + k], wk, a1);
        a2 = fmaf(xs[(rg * 4 + 2) * HID + k], wk, a2);
        a3 = fmaf(xs[(rg * 4 + 3) * HID + k], wk, a3);
    }
    float bb = b[col];
    size_t r = rowbase + rg * 4;
    z1[(r + 0) * HID + col] = a0 + bb;
    z1[(r + 1) * HID + col] = a1 + bb;
    z1[(r + 2) * HID + col] = a2 + bb;
    z1[(r + 3) * HID + col] = a3 + bb;
}

__global__ __launch_bounds__(256) void mlp2_kernel(const float* __restrict__ z1, const float* __restrict__ scale,
                                                   const float* __restrict__ shift, const float* __restrict__ W,
                                                   const float* __restrict__ b, float* __restrict__ z2) {
    __shared__ float Wl[HID * H2];
    __shared__ float as[16 * HID];
    int t = threadIdx.x;
    for (int i = t; i < HID * H2; i += 256) Wl[i] = W[i];
    size_t rowbase = (size_t)blockIdx.x * 16;
    for (int i = t; i < 16 * HID; i += 256) {
        int c = i & 63;
        float v = z1[rowbase * HID + i];
        as[i] = fmaxf(fmaf(v, scale[c], shift[c]), 0.f);
    }
    __syncthreads();
    int col = t & 31, rg = t >> 5;
    float a0 = 0.f, a1 = 0.f;
    for (int k = 0; k < HID; k++) {
        float wk = Wl[k * H2 + col];
        a0 = fmaf(as[(rg * 2 + 0) * HID + k], wk, a0);
        a1 = fmaf(as[(rg * 2 + 1) * HID + k], wk, a1);
    }
    float bb = b[col];
    size_t r = rowbase + rg * 2;
    z2[(r + 0) * H2 + col] = a0 + bb;
    z2[(r + 1) * H2 + col] = a1 + bb;
}

__global__ __launch_bounds__(256) void mlp3_kernel(const float* __restrict__ z2, const float* __restrict__ scale,
                                                   const float* __restrict__ shift, const float* __restrict__ W3,
                                                   const float* __restrict__ b3, float* __restrict__ out, int rows) {
    int i = blockIdx.x * 256 + threadIdx.x;
    if (i >= rows) return;
    float acc = 0.f;
#pragma unroll
    for (int k = 0; k < H2; k++) {
        float v = fmaxf(fmaf(z2[(size_t)i * H2 + k], scale[k], shift[k]), 0.f);
        acc = fmaf(v, W3[k], acc);
    }
    out[i] = acc + b3[0];
}

// ---------------- launch ----------------
extern "C" void kernel_launch(void* const* d_in, const int* in_sizes, int n_in,
                              void* d_out, int out_size, void* d_ws, size_t ws_size,
                              hipStream_t stream) {
    const float* x     = (const float*)d_in[0];
    const int*   ei    = (const int*)d_in[1];
    const int*   src   = ei;
    const int*   dst   = ei + NE;
    const float* W_in  = (const float*)d_in[3];
    const float* b_in  = (const float*)d_in[4];
    const float* att_l = (const float*)d_in[5];
    const float* att_r = (const float*)d_in[6];
    const float* bn_g  = (const float*)d_in[7];
    const float* bn_b  = (const float*)d_in[8];
    const float* W1    = (const float*)d_in[9];
    const float* b1    = (const float*)d_in[10];
    const float* g1    = (const float*)d_in[11];
    const float* be1   = (const float*)d_in[12];
    const float* W2    = (const float*)d_in[13];
    const float* b2    = (const float*)d_in[14];
    const float* g2    = (const float*)d_in[15];
    const float* be2   = (const float*)d_in[16];
    const float* W3    = (const float*)d_in[17];
    const float* b3    = (const float*)d_in[18];
    float* out = (float*)d_out;

    char* p = (char*)d_ws;
    auto carve = [&](size_t bytes) -> void* {
        void* r = (void*)p;
        p += (bytes + 255) & ~(size_t)255;
        return r;
    };
    int*   bh_part = (int*)carve((size_t)NHB * 256 * 4);
    int*   bstart  = (int*)carve(256 * 4);
    int*   bcur    = (int*)carve(256 * 4);
    int*   offsets = (int*)carve((size_t)(NND + 1) * 4);
    int*   csr     = (int*)carve((size_t)TOT * 4);
    float* dinv    = (float*)carve((size_t)NND * 4);
    float* al      = (float*)carve((size_t)NND * 4);
    float* ar      = (float*)carve((size_t)NND * 4);
    __hip_bfloat16* x0bf = (__hip_bfloat16*)carve((size_t)NND * HID * 2);
    __hip_bfloat16* hbfA = (__hip_bfloat16*)carve((size_t)NND * HID * 2);
    __hip_bfloat16* hbfB = (__hip_bfloat16*)carve((size_t)NND * HID * 2);
    float* ybuf    = (float*)carve((size_t)NND * HID * 4);
    int2*  ebuf    = (int2*)ybuf;   // alias: ebuf (9.6 MB) lifetime ends before ybuf first write
    float* bn_part = (float*)carve((size_t)NSTAT * 128 * 4);
    float* scale   = (float*)carve(64 * 4);
    float* shift   = (float*)carve(64 * 4);
    float* z1      = (float*)carve((size_t)BSZ * HID * 4);
    float* z2      = (float*)carve((size_t)BSZ * H2 * 4);

    const int nblkA = (NE + CHUNK - 1) / CHUNK; // 293

    // --- binned CSR build (4 dispatches, no memsets) ---
    bhist_kernel<<<NHB, 256, 0, stream>>>(dst, bh_part, NE);
    bscan_kernel<<<1, 256, 0, stream>>>(bh_part, bstart, bcur, offsets);
    passA_kernel<<<nblkA, 256, 0, stream>>>(src, dst, bcur, ebuf, NE);
    bucket_build_kernel<<<NB, 256, 0, stream>>>(ebuf, bstart, offsets, csr, dinv);

    // --- input projection (+ attn dots layer 0) ---
    gemm_in_kernel<<<NND / 16, 256, 0, stream>>>(x, W_in, b_in, att_l, att_r, x0bf, al, ar);

    // --- 3 layers ---
    const __hip_bfloat16* h_in = x0bf;
    __hip_bfloat16* hbufs[2] = {hbfA, hbfB};
    for (int l = 0; l < NL; l++) {
        aggregate_kernel<<<NND / 4, 256, 0, stream>>>(h_in, x0bf, al, ar, dinv, offsets, csr, ybuf, NND);
        bn_stats_kernel<64><<<NSTAT, 256, 0, stream>>>(ybuf, NND, bn_part);
        bn_finalize_kernel<<<1, 256, 0, stream>>>(bn_part, NSTAT, bn_g + l * HID, bn_b + l * HID,
                                                  1.0f / NND, HID, scale, shift);
        if (l < NL - 1) {
            bnapply_attn_kernel<<<NND / 4, 256, 0, stream>>>(ybuf, scale, shift,
                                                             att_l + (l + 1) * HID, att_r + (l + 1) * HID,
                                                             hbufs[l], al, ar, NND);
            h_in = hbufs[l];
        }
        // last layer: BN fused into mlp1 staging
    }

    // --- MLP head ---
    mlp1_kernel<<<BSZ / 16, 256, 0, stream>>>(ybuf, scale, shift, W1, b1, z1);
    bn_stats_kernel<64><<<NSTAT, 256, 0, stream>>>(z1, BSZ, bn_part);
    bn_finalize_kernel<<<1, 256, 0, stream>>>(bn_part, NSTAT, g1, be1, 1.0f / BSZ, HID, scale, shift);

    mlp2_kernel<<<BSZ / 16, 256, 0, stream>>>(z1, scale, shift, W2, b2, z2);
    bn_stats_kernel<32><<<NSTAT, 256, 0, stream>>>(z2, BSZ, bn_part);
    bn_finalize_kernel<<<1, 256, 0, stream>>>(bn_part, NSTAT, g2, be2, 1.0f / BSZ, H2, scale, shift);

    mlp3_kernel<<<(BSZ + 255) / 256, 256, 0, stream>>>(z2, scale, shift, W3, b3, out, BSZ);
}

// Round 11
// 376.467 us; speedup vs baseline: 1.7894x; 1.1534x over previous
//
#include <hip/hip_runtime.h>
#include <hip/hip_bf16.h>
#include <math.h>

#define NND 50000
#define NE  1200000
#define TOT (NE + NND)
#define INCH 128
#define HID 64
#define H2  32
#define NL  3
#define BSZ 10000
#define NB  196          // ceil(NND/256) dst-buckets of 256 nodes
#define NHB 128          // bhist partial blocks
#define NSTAT 256        // bn_stats blocks
#define CHUNK 4096       // edges per passA block
#define EPS_RES 0.1f
#define BN_EPS 1e-5f

typedef unsigned short ushort8v __attribute__((ext_vector_type(8)));

__device__ __forceinline__ float b2f(unsigned short u) {
    return __uint_as_float((unsigned)u << 16);
}

// ---------------- binned CSR build ----------------
// ebuf entry: (src << 8) | (dst & 255)   [src < 2^16, 8-bit local dst -> 24 bits]

__global__ __launch_bounds__(256) void bhist_kernel(const int* __restrict__ dst, int* __restrict__ bh_part, int ne) {
    __shared__ int arr[256];
    arr[threadIdx.x] = 0;
    __syncthreads();
    int i = blockIdx.x * 256 + threadIdx.x;
    int stride = gridDim.x * 256;
    for (int e = i; e < ne; e += stride) atomicAdd(&arr[dst[e] >> 8], 1);
    __syncthreads();
    bh_part[blockIdx.x * 256 + threadIdx.x] = arr[threadIdx.x];
}

__global__ __launch_bounds__(256) void bscan_kernel(const int* __restrict__ bh_part,
                                                    int* __restrict__ bstart, int* __restrict__ bcur,
                                                    int* __restrict__ offsets) {
    __shared__ int ls[256];
    int t = threadIdx.x;
    int v = 0;
    for (int k = 0; k < NHB; k++) v += bh_part[k * 256 + t];
    ls[t] = v;
    __syncthreads();
    for (int off = 1; off < 256; off <<= 1) {
        int tv = (t >= off) ? ls[t - off] : 0;
        __syncthreads();
        ls[t] += tv;
        __syncthreads();
    }
    int excl = ls[t] - v;
    if (t < NB) { bstart[t] = excl; bcur[t] = excl; }
    if (t == NB) bstart[NB] = ls[NB - 1];   // = NE
    if (t == 0) offsets[NND] = TOT;
}

// binned scatter with packed 4B entries
__global__ __launch_bounds__(256) void passA_kernel(const int* __restrict__ src, const int* __restrict__ dst,
                                                    int* __restrict__ bcur, unsigned* __restrict__ ebuf, int ne) {
    __shared__ int arr[256];
    int t = threadIdx.x;
    int base = blockIdx.x * CHUNK;
    int lim = min(base + CHUNK, ne);
    arr[t] = 0;
    __syncthreads();
    for (int e = base + t; e < lim; e += 256) atomicAdd(&arr[dst[e] >> 8], 1);
    __syncthreads();
    int cnt_t = arr[t];
    int claimed = 0;
    if (cnt_t > 0) claimed = atomicAdd(&bcur[t], cnt_t);
    __syncthreads();
    arr[t] = claimed;
    __syncthreads();
    for (int e = base + t; e < lim; e += 256) {
        int d = dst[e];
        int pos = atomicAdd(&arr[d >> 8], 1);
        ebuf[pos] = ((unsigned)src[e] << 8) | (unsigned)(d & 255);
    }
}

// fused: per-bucket degree + local offset scan + dinv + self-loop + edge placement
__global__ __launch_bounds__(256) void bucket_build_kernel(const unsigned* __restrict__ ebuf, const int* __restrict__ bstart,
                                                           int* __restrict__ offsets, int* __restrict__ csr,
                                                           float* __restrict__ dinv) {
    __shared__ int dcnt[256];
    __shared__ int ls[256];
    __shared__ int cur[256];
    int b = blockIdx.x, t = threadIdx.x;
    dcnt[t] = 0;
    __syncthreads();
    int beg = bstart[b], end = bstart[b + 1];
    for (int p = beg + t; p < end; p += 256) atomicAdd(&dcnt[ebuf[p] & 255u], 1);
    __syncthreads();
    int node = b * 256 + t;
    bool valid = node < NND;
    int d = valid ? (dcnt[t] + 1) : 0;       // +1 self-loop
    ls[t] = d;
    __syncthreads();
    for (int off = 1; off < 256; off <<= 1) {
        int tv = (t >= off) ? ls[t - off] : 0;
        __syncthreads();
        ls[t] += tv;
        __syncthreads();
    }
    int off = bstart[b] + b * 256 + ls[t] - d;   // exclusive
    if (valid) {
        offsets[node] = off;
        dinv[node] = rsqrtf((float)d);
        csr[off] = node;        // self-loop first
        cur[t] = off + 1;
    }
    __syncthreads();
    for (int p = beg + t; p < end; p += 256) {
        unsigned ed = ebuf[p];
        int pos = atomicAdd(&cur[ed & 255u], 1);
        csr[pos] = (int)(ed >> 8);
    }
}

// ---------------- input projection: x0 = relu(x @ W_in + b_in) -> bf16, fused attn layer 0 ----------------
__global__ __launch_bounds__(256) void gemm_in_kernel(const float* __restrict__ x, const float* __restrict__ W,
                                                      const float* __restrict__ b,
                                                      const float* __restrict__ attl, const float* __restrict__ attr,
                                                      __hip_bfloat16* __restrict__ x0bf,
                                                      float* __restrict__ al, float* __restrict__ ar) {
    __shared__ float Wl[INCH * HID];   // 32 KB
    __shared__ float xs[16 * INCH];    // 8 KB
    int t = threadIdx.x;
    for (int i = t; i < INCH * HID; i += 256) Wl[i] = W[i];
    size_t rowbase = (size_t)blockIdx.x * 16;
    for (int i = t; i < 16 * INCH; i += 256) xs[i] = x[rowbase * INCH + i];
    __syncthreads();
    int col = t & 63, rg = t >> 6;
    float a0 = 0.f, a1 = 0.f, a2 = 0.f, a3 = 0.f;
    for (int k = 0; k < INCH; k++) {
        float wk = Wl[k * HID + col];
        a0 = fmaf(xs[(rg * 4 + 0) * INCH + k], wk, a0);
        a1 = fmaf(xs[(rg * 4 + 1) * INCH + k], wk, a1);
        a2 = fmaf(xs[(rg * 4 + 2) * INCH + k], wk, a2);
        a3 = fmaf(xs[(rg * 4 + 3) * INCH + k], wk, a3);
    }
    float bb = b[col];
    a0 = fmaxf(a0 + bb, 0.f); a1 = fmaxf(a1 + bb, 0.f);
    a2 = fmaxf(a2 + bb, 0.f); a3 = fmaxf(a3 + bb, 0.f);
    size_t r = rowbase + rg * 4;
    x0bf[(r + 0) * HID + col] = __float2bfloat16(a0);
    x0bf[(r + 1) * HID + col] = __float2bfloat16(a1);
    x0bf[(r + 2) * HID + col] = __float2bfloat16(a2);
    x0bf[(r + 3) * HID + col] = __float2bfloat16(a3);
    float wl = attl[col], wr = attr[col];
    float p0 = a0 * wl, q0 = a0 * wr, p1 = a1 * wl, q1 = a1 * wr;
    float p2 = a2 * wl, q2 = a2 * wr, p3 = a3 * wl, q3 = a3 * wr;
    for (int off = 32; off > 0; off >>= 1) {
        p0 += __shfl_xor(p0, off); q0 += __shfl_xor(q0, off);
        p1 += __shfl_xor(p1, off); q1 += __shfl_xor(q1, off);
        p2 += __shfl_xor(p2, off); q2 += __shfl_xor(q2, off);
        p3 += __shfl_xor(p3, off); q3 += __shfl_xor(q3, off);
    }
    if (col == 0) {
        al[r + 0] = p0; ar[r + 0] = q0;
        al[r + 1] = p1; ar[r + 1] = q1;
        al[r + 2] = p2; ar[r + 2] = q2;
        al[r + 3] = p3; ar[r + 3] = q3;
    }
}

// ---------------- aggregate: 8 edge-groups x 8 lanes, ushort8 (16B) bf16 loads ----------------
__global__ __launch_bounds__(256) void aggregate_kernel(const __hip_bfloat16* __restrict__ hbf,
                                                        const __hip_bfloat16* __restrict__ x0bf,
                                                        const float* __restrict__ al, const float* __restrict__ ar,
                                                        const float* __restrict__ dinv,
                                                        const int* __restrict__ offsets, const int* __restrict__ csr,
                                                        float* __restrict__ y, int n) {
    int v = (blockIdx.x * 256 + threadIdx.x) >> 6;
    int lane = threadIdx.x & 63;
    if (v >= n) return;
    int g = lane >> 3;           // edge subgroup 0..7
    int cl = (lane & 7) << 3;    // channel base (8 channels per lane)
    int beg = offsets[v], end = offsets[v + 1];
    float arv = ar[v];
    float a0 = 0.f, a1 = 0.f, a2 = 0.f, a3 = 0.f, a4 = 0.f, a5 = 0.f, a6 = 0.f, a7 = 0.f;
    for (int base = beg; base < end; base += 64) {
        int p = base + lane;
        int u = 0; float c = 0.f;
        if (p < end) {
            u = csr[p];
            c = tanhf(al[u] + arv) * dinv[u];   // dinv[v] factored out
        }
        int cnt = min(64, end - base);
        int iters = (cnt + 7) >> 3;             // uniform across all lanes
        for (int it = 0; it < iters; ++it) {
            int j = (it << 3) + g;
            int js = (j < cnt) ? j : 0;         // clamp: shfl source always valid+active
            int uj = __shfl(u, js);
            float cj = __shfl(c, js);
            if (j < cnt) {
                ushort8v hv = *(const ushort8v*)((const unsigned short*)hbf + (size_t)uj * HID + cl);
                a0 = fmaf(b2f(hv[0]), cj, a0);
                a1 = fmaf(b2f(hv[1]), cj, a1);
                a2 = fmaf(b2f(hv[2]), cj, a2);
                a3 = fmaf(b2f(hv[3]), cj, a3);
                a4 = fmaf(b2f(hv[4]), cj, a4);
                a5 = fmaf(b2f(hv[5]), cj, a5);
                a6 = fmaf(b2f(hv[6]), cj, a6);
                a7 = fmaf(b2f(hv[7]), cj, a7);
            }
        }
    }
    for (int off = 8; off < 64; off <<= 1) {
        a0 += __shfl_xor(a0, off); a1 += __shfl_xor(a1, off);
        a2 += __shfl_xor(a2, off); a3 += __shfl_xor(a3, off);
        a4 += __shfl_xor(a4, off); a5 += __shfl_xor(a5, off);
        a6 += __shfl_xor(a6, off); a7 += __shfl_xor(a7, off);
    }
    if (g == 0) {
        float dv = dinv[v];
        ushort8v xb = *(const ushort8v*)((const unsigned short*)x0bf + (size_t)v * HID + cl);
        float4 o0, o1;
        o0.x = fmaxf(fmaf(EPS_RES, b2f(xb[0]), a0 * dv), 0.f);
        o0.y = fmaxf(fmaf(EPS_RES, b2f(xb[1]), a1 * dv), 0.f);
        o0.z = fmaxf(fmaf(EPS_RES, b2f(xb[2]), a2 * dv), 0.f);
        o0.w = fmaxf(fmaf(EPS_RES, b2f(xb[3]), a3 * dv), 0.f);
        o1.x = fmaxf(fmaf(EPS_RES, b2f(xb[4]), a4 * dv), 0.f);
        o1.y = fmaxf(fmaf(EPS_RES, b2f(xb[5]), a5 * dv), 0.f);
        o1.z = fmaxf(fmaf(EPS_RES, b2f(xb[6]), a6 * dv), 0.f);
        o1.w = fmaxf(fmaf(EPS_RES, b2f(xb[7]), a7 * dv), 0.f);
        *(float4*)(y + (size_t)v * HID + cl) = o0;
        *(float4*)(y + (size_t)v * HID + cl + 4) = o1;
    }
}

// ---------------- fused batchnorm stats+finalize (last-block pattern, self-resetting) ----------------
// acc[0..63]=sum, acc[64..127]=sumsq, counter after. Requires acc+counter zeroed ONCE at call start;
// last block computes scale/shift and resets acc/counter for the next use (atomics = L2-coherent, XCD-safe).
template <int C>
__global__ __launch_bounds__(256) void bn_stats_fused_kernel(const float* __restrict__ y, int rows,
                                                             const float* __restrict__ g, const float* __restrict__ b,
                                                             float rows_inv,
                                                             float* __restrict__ acc, int* __restrict__ counter,
                                                             float* __restrict__ scale, float* __restrict__ shift) {
    const int TPR = C / 4;           // lanes per row
    const int RPW = 64 / TPR;        // rows per wave per iter
    int lane = threadIdx.x & 63;
    int wave = threadIdx.x >> 6;
    int cl = (lane % TPR) * 4;
    int rsub = lane / TPR;
    int rpb = 4 * RPW;
    int r = blockIdx.x * rpb + wave * RPW + rsub;
    int stride = gridDim.x * rpb;
    float s0 = 0.f, s1 = 0.f, s2 = 0.f, s3 = 0.f, q0 = 0.f, q1 = 0.f, q2 = 0.f, q3 = 0.f;
    for (; r < rows; r += stride) {
        float4 v = *(const float4*)(y + (size_t)r * C + cl);
        s0 += v.x; q0 = fmaf(v.x, v.x, q0);
        s1 += v.y; q1 = fmaf(v.y, v.y, q1);
        s2 += v.z; q2 = fmaf(v.z, v.z, q2);
        s3 += v.w; q3 = fmaf(v.w, v.w, q3);
    }
    for (int off = TPR; off < 64; off <<= 1) {
        s0 += __shfl_xor(s0, off); q0 += __shfl_xor(q0, off);
        s1 += __shfl_xor(s1, off); q1 += __shfl_xor(q1, off);
        s2 += __shfl_xor(s2, off); q2 += __shfl_xor(q2, off);
        s3 += __shfl_xor(s3, off); q3 += __shfl_xor(q3, off);
    }
    __shared__ float lsum[4][64], lsq[4][64];
    if (lane < TPR) {
        lsum[wave][cl + 0] = s0; lsq[wave][cl + 0] = q0;
        lsum[wave][cl + 1] = s1; lsq[wave][cl + 1] = q1;
        lsum[wave][cl + 2] = s2; lsq[wave][cl + 2] = q2;
        lsum[wave][cl + 3] = s3; lsq[wave][cl + 3] = q3;
    }
    __syncthreads();
    int t = threadIdx.x;
    if (t < C) {
        float ts = lsum[0][t] + lsum[1][t] + lsum[2][t] + lsum[3][t];
        float tq = lsq[0][t] + lsq[1][t] + lsq[2][t] + lsq[3][t];
        atomicAdd(&acc[t], ts);
        atomicAdd(&acc[64 + t], tq);
    }
    __shared__ int islast;
    __syncthreads();
    if (t == 0) {
        __threadfence();
        int old = atomicAdd(counter, 1);
        islast = (old == (int)gridDim.x - 1) ? 1 : 0;
    }
    __syncthreads();
    if (islast && t < C) {
        float ts = atomicAdd(&acc[t], 0.f);        // atomic read (coherent)
        float tq = atomicAdd(&acc[64 + t], 0.f);
        float mean = ts * rows_inv;
        float var = tq * rows_inv - mean * mean;
        float sc = g[t] * rsqrtf(var + BN_EPS);
        scale[t] = sc;
        shift[t] = b[t] - mean * sc;
        atomicExch(&acc[t], 0.f);                  // self-reset for next use
        atomicExch(&acc[64 + t], 0.f);
        if (t == 0) atomicExch(counter, 0);
    }
}

// BN apply + attention dots for next layer; writes ONLY bf16 h
__global__ __launch_bounds__(256) void bnapply_attn_kernel(const float* __restrict__ y, const float* __restrict__ scale,
                                                           const float* __restrict__ shift,
                                                           const float* __restrict__ attl, const float* __restrict__ attr,
                                                           __hip_bfloat16* __restrict__ hbf,
                                                           float* __restrict__ al, float* __restrict__ ar, int n) {
    int v = (blockIdx.x * 256 + threadIdx.x) >> 6;
    int lane = threadIdx.x & 63;
    if (v >= n) return;
    float val = fmaf(y[(size_t)v * HID + lane], scale[lane], shift[lane]);
    hbf[(size_t)v * HID + lane] = __float2bfloat16(val);
    float pl = val * attl[lane];
    float pr = val * attr[lane];
    for (int off = 32; off > 0; off >>= 1) {
        pl += __shfl_xor(pl, off);
        pr += __shfl_xor(pr, off);
    }
    if (lane == 0) { al[v] = pl; ar[v] = pr; }
}

// ---------------- MLP head ----------------
__global__ __launch_bounds__(256) void mlp1_kernel(const float* __restrict__ y, const float* __restrict__ scale,
                                                   const float* __restrict__ shift, const float* __restrict__ W,
                                                   const float* __restrict__ b, float* __restrict__ z1) {
    __shared__ float Wl[HID * HID];
    __shared__ float xs[16 * HID];
    int t = threadIdx.x;
    for (int i = t; i < HID * HID; i += 256) Wl[i] = W[i];
    size_t rowbase = (size_t)blockIdx.x * 16;
    for (int i = t; i < 16 * HID; i += 256) {
        int c = i & 63;
        xs[i] = fmaf(y[rowbase * HID + i], scale[c], shift[c]);
    }
    __syncthreads();
    int col = t & 63, rg = t >> 6;
    float a0 = 0.f, a1 = 0.f, a2 = 0.f, a3 = 0.f;
    for (int k = 0; k < HID; k++) {
        float wk = Wl[k * HID + col];
        a0 = fmaf(xs[(rg * 4 + 0) * HID + k], wk, a0);
        a1 = fmaf(xs[(rg * 4 + 1) * HID + k], wk, a1);
        a2 = fmaf(xs[(rg * 4 + 2) * HID + k], wk, a2);
        a3 = fmaf(xs[(rg * 4 + 3) * HID + k], wk, a3);
    }
    float bb = b[col];
    size_t r = rowbase + rg * 4;
    z1[(r + 0) * HID + col] = a0 + bb;
    z1[(r + 1) * HID + col] = a1 + bb;
    z1[(r + 2) * HID + col] = a2 + bb;
    z1[(r + 3) * HID + col] = a3 + bb;
}

__global__ __launch_bounds__(256) void mlp2_kernel(const float* __restrict__ z1, const float* __restrict__ scale,
                                                   const float* __restrict__ shift, const float* __restrict__ W,
                                                   const float* __restrict__ b, float* __restrict__ z2) {
    __shared__ float Wl[HID * H2];
    __shared__ float as[16 * HID];
    int t = threadIdx.x;
    for (int i = t; i < HID * H2; i += 256) Wl[i] = W[i];
    size_t rowbase = (size_t)blockIdx.x * 16;
    for (int i = t; i < 16 * HID; i += 256) {
        int c = i & 63;
        float v = z1[rowbase * HID + i];
        as[i] = fmaxf(fmaf(v, scale[c], shift[c]), 0.f);
    }
    __syncthreads();
    int col = t & 31, rg = t >> 5;
    float a0 = 0.f, a1 = 0.f;
    for (int k = 0; k < HID; k++) {
        float wk = Wl[k * H2 + col];
        a0 = fmaf(as[(rg * 2 + 0) * HID + k], wk, a0);
        a1 = fmaf(as[(rg * 2 + 1) * HID + k], wk, a1);
    }
    float bb = b[col];
    size_t r = rowbase + rg * 2;
    z2[(r + 0) * H2 + col] = a0 + bb;
    z2[(r + 1) * H2 + col] = a1 + bb;
}

__global__ __launch_bounds__(256) void mlp3_kernel(const float* __restrict__ z2, const float* __restrict__ scale,
                                                   const float* __restrict__ shift, const float* __restrict__ W3,
                                                   const float* __restrict__ b3, float* __restrict__ out, int rows) {
    int i = blockIdx.x * 256 + threadIdx.x;
    if (i >= rows) return;
    float acc = 0.f;
#pragma unroll
    for (int k = 0; k < H2; k++) {
        float v = fmaxf(fmaf(z2[(size_t)i * H2 + k], scale[k], shift[k]), 0.f);
        acc = fmaf(v, W3[k], acc);
    }
    out[i] = acc + b3[0];
}

// ---------------- launch ----------------
extern "C" void kernel_launch(void* const* d_in, const int* in_sizes, int n_in,
                              void* d_out, int out_size, void* d_ws, size_t ws_size,
                              hipStream_t stream) {
    const float* x     = (const float*)d_in[0];
    const int*   ei    = (const int*)d_in[1];
    const int*   src   = ei;
    const int*   dst   = ei + NE;
    const float* W_in  = (const float*)d_in[3];
    const float* b_in  = (const float*)d_in[4];
    const float* att_l = (const float*)d_in[5];
    const float* att_r = (const float*)d_in[6];
    const float* bn_g  = (const float*)d_in[7];
    const float* bn_b  = (const float*)d_in[8];
    const float* W1    = (const float*)d_in[9];
    const float* b1    = (const float*)d_in[10];
    const float* g1    = (const float*)d_in[11];
    const float* be1   = (const float*)d_in[12];
    const float* W2    = (const float*)d_in[13];
    const float* b2    = (const float*)d_in[14];
    const float* g2    = (const float*)d_in[15];
    const float* be2   = (const float*)d_in[16];
    const float* W3    = (const float*)d_in[17];
    const float* b3    = (const float*)d_in[18];
    float* out = (float*)d_out;

    char* p = (char*)d_ws;
    auto carve = [&](size_t bytes) -> void* {
        void* r = (void*)p;
        p += (bytes + 255) & ~(size_t)255;
        return r;
    };
    int*   bh_part = (int*)carve((size_t)NHB * 256 * 4);
    int*   bstart  = (int*)carve(256 * 4);
    int*   bcur    = (int*)carve(256 * 4);
    int*   offsets = (int*)carve((size_t)(NND + 1) * 4);
    int*   csr     = (int*)carve((size_t)TOT * 4);
    float* dinv    = (float*)carve((size_t)NND * 4);
    float* al      = (float*)carve((size_t)NND * 4);
    float* ar      = (float*)carve((size_t)NND * 4);
    __hip_bfloat16* x0bf = (__hip_bfloat16*)carve((size_t)NND * HID * 2);
    __hip_bfloat16* hbfA = (__hip_bfloat16*)carve((size_t)NND * HID * 2);
    __hip_bfloat16* hbfB = (__hip_bfloat16*)carve((size_t)NND * HID * 2);
    float* ybuf    = (float*)carve((size_t)NND * HID * 4);
    unsigned* ebuf = (unsigned*)ybuf;   // alias: ebuf (4.8 MB) lifetime ends before ybuf first write
    float* acc     = (float*)carve(132 * 4);   // 128 accum + counter
    int*   counter = (int*)(acc + 128);
    float* scale   = (float*)carve(64 * 4);
    float* shift   = (float*)carve(64 * 4);
    float* z1      = (float*)carve((size_t)BSZ * HID * 4);
    float* z2      = (float*)carve((size_t)BSZ * H2 * 4);

    const int nblkA = (NE + CHUNK - 1) / CHUNK; // 293

    // zero the BN accumulator + counter once; bn_stats_fused self-resets afterwards
    hipMemsetAsync(acc, 0, 132 * 4, stream);

    // --- binned CSR build; gemm_in launched early to overlap the 1-block bscan ---
    bhist_kernel<<<NHB, 256, 0, stream>>>(dst, bh_part, NE);
    gemm_in_kernel<<<NND / 16, 256, 0, stream>>>(x, W_in, b_in, att_l, att_r, x0bf, al, ar);
    bscan_kernel<<<1, 256, 0, stream>>>(bh_part, bstart, bcur, offsets);
    passA_kernel<<<nblkA, 256, 0, stream>>>(src, dst, bcur, ebuf, NE);
    bucket_build_kernel<<<NB, 256, 0, stream>>>(ebuf, bstart, offsets, csr, dinv);

    // --- 3 layers ---
    const __hip_bfloat16* h_in = x0bf;
    __hip_bfloat16* hbufs[2] = {hbfA, hbfB};
    for (int l = 0; l < NL; l++) {
        aggregate_kernel<<<NND / 4, 256, 0, stream>>>(h_in, x0bf, al, ar, dinv, offsets, csr, ybuf, NND);
        bn_stats_fused_kernel<64><<<NSTAT, 256, 0, stream>>>(ybuf, NND, bn_g + l * HID, bn_b + l * HID,
                                                             1.0f / NND, acc, counter, scale, shift);
        if (l < NL - 1) {
            bnapply_attn_kernel<<<NND / 4, 256, 0, stream>>>(ybuf, scale, shift,
                                                             att_l + (l + 1) * HID, att_r + (l + 1) * HID,
                                                             hbufs[l], al, ar, NND);
            h_in = hbufs[l];
        }
        // last layer: BN fused into mlp1 staging
    }

    // --- MLP head ---
    mlp1_kernel<<<BSZ / 16, 256, 0, stream>>>(ybuf, scale, shift, W1, b1, z1);
    bn_stats_fused_kernel<64><<<NSTAT, 256, 0, stream>>>(z1, BSZ, g1, be1, 1.0f / BSZ, acc, counter, scale, shift);

    mlp2_kernel<<<BSZ / 16, 256, 0, stream>>>(z1, scale, shift, W2, b2, z2);
    bn_stats_fused_kernel<32><<<NSTAT, 256, 0, stream>>>(z2, BSZ, g2, be2, 1.0f / BSZ, acc, counter, scale, shift);

    mlp3_kernel<<<(BSZ + 255) / 256, 256, 0, stream>>>(z2, scale, shift, W3, b3, out, BSZ);
}